// Round 1
// baseline (4894.546 us; speedup 1.0000x reference)
//
#include <hip/hip_runtime.h>
#include <hip/hip_bf16.h>
#include <math.h>

#define N_NODES 100000
#define N_EDGES 1600000
#define NFEAT 256
#define NHID1 128
#define NCLASS 64
#define NUM_GRAPHS 64

// ---------------- degree / norm ----------------

__global__ void init_deg_kernel(float* deg, int n) {
    int i = blockIdx.x * blockDim.x + threadIdx.x;
    if (i < n) deg[i] = 1.0f;  // self-loop weight
}

__global__ void deg_scatter_kernel(const int* __restrict__ cols,
                                   const float* __restrict__ w,
                                   float* __restrict__ deg, int nE) {
    int e = blockIdx.x * blockDim.x + threadIdx.x;
    if (e < nE) atomicAdd(&deg[cols[e]], w[e]);
}

__global__ void dinv_kernel(const float* __restrict__ deg, float* __restrict__ dinv, int n) {
    int i = blockIdx.x * blockDim.x + threadIdx.x;
    if (i < n) {
        float d = deg[i];
        dinv[i] = (d > 0.f) ? rsqrtf(d) : 0.f;
    }
}

// ---------------- tiled f32 GEMM: C[M,N] = A[M,K] @ B[K,N] ----------------
// 64x64 tile, BK=16, 256 threads, 4x4 micro-tile per thread.
// Requires K % 16 == 0 and N % 64 == 0 (true here: K=256/128, N=128/64).

__global__ __launch_bounds__(256) void gemm_f32_kernel(const float* __restrict__ A,
                                                       const float* __restrict__ B,
                                                       float* __restrict__ C,
                                                       int M, int K, int N) {
    __shared__ float As[16][68];  // +4 pad: keeps float4 alignment, breaks bank stride
    __shared__ float Bs[16][64];
    const int tid = threadIdx.x;
    const int tx = tid & 15;       // col group 0..15
    const int ty = tid >> 4;       // row group 0..15
    const int row0 = blockIdx.x * 64;
    const int col0 = blockIdx.y * 64;

    float acc[4][4] = {};

    for (int k0 = 0; k0 < K; k0 += 16) {
        // load A tile 64x16 (4 elems/thread)
        #pragma unroll
        for (int i = 0; i < 4; i++) {
            int idx = tid + i * 256;
            int m = idx >> 4;
            int k = idx & 15;
            int gr = row0 + m;
            As[k][m] = (gr < M) ? A[(long)gr * K + k0 + k] : 0.f;
        }
        // load B tile 16x64
        #pragma unroll
        for (int i = 0; i < 4; i++) {
            int idx = tid + i * 256;
            int k = idx >> 6;
            int n = idx & 63;
            Bs[k][n] = B[(long)(k0 + k) * N + col0 + n];
        }
        __syncthreads();
        #pragma unroll
        for (int k = 0; k < 16; k++) {
            float4 a = *(const float4*)&As[k][ty * 4];
            float4 b = *(const float4*)&Bs[k][tx * 4];
            acc[0][0] += a.x * b.x; acc[0][1] += a.x * b.y; acc[0][2] += a.x * b.z; acc[0][3] += a.x * b.w;
            acc[1][0] += a.y * b.x; acc[1][1] += a.y * b.y; acc[1][2] += a.y * b.z; acc[1][3] += a.y * b.w;
            acc[2][0] += a.z * b.x; acc[2][1] += a.z * b.y; acc[2][2] += a.z * b.z; acc[2][3] += a.z * b.w;
            acc[3][0] += a.w * b.x; acc[3][1] += a.w * b.y; acc[3][2] += a.w * b.z; acc[3][3] += a.w * b.w;
        }
        __syncthreads();
    }

    #pragma unroll
    for (int i = 0; i < 4; i++) {
        int gr = row0 + ty * 4 + i;
        if (gr < M) {
            float4 v = make_float4(acc[i][0], acc[i][1], acc[i][2], acc[i][3]);
            *(float4*)&C[(long)gr * N + col0 + tx * 4] = v;
        }
    }
}

// ---------------- edge scatter: dst[col] += src[row] * norm ----------------
// F4 = F/4 lanes per edge, float4 gather + 4 atomic adds.

__global__ void scatter_edges_kernel(const float* __restrict__ src,
                                     const int* __restrict__ rows,
                                     const int* __restrict__ cols,
                                     const float* __restrict__ w,
                                     const float* __restrict__ dinv,
                                     float* __restrict__ dst,
                                     int nE, int F) {
    const int F4 = F >> 2;
    long tid = (long)blockIdx.x * blockDim.x + threadIdx.x;
    long e = tid / F4;
    int lane = (int)(tid - e * F4);
    if (e >= nE) return;
    int r = rows[e], c = cols[e];
    float norm = dinv[r] * w[e] * dinv[c];
    float4 v = ((const float4*)(src + (long)r * F))[lane];
    float* o = dst + (long)c * F + lane * 4;
    atomicAdd(o + 0, v.x * norm);
    atomicAdd(o + 1, v.y * norm);
    atomicAdd(o + 2, v.z * norm);
    atomicAdd(o + 3, v.w * norm);
}

// ---------------- finalize: h = relu(agg + xw*dinv^2 + b) (in place into agg) ----------------

__global__ void finalize_kernel(float* __restrict__ agg,
                                const float* __restrict__ xw,
                                const float* __restrict__ dinv,
                                const float* __restrict__ b,
                                int n, int F) {
    const int F4 = F >> 2;
    long tid = (long)blockIdx.x * blockDim.x + threadIdx.x;
    long total = (long)n * F4;
    if (tid >= total) return;
    long i = tid / F4;
    int lane = (int)(tid - i * F4);
    float d = dinv[i];
    float s = d * d;
    float4 a = ((const float4*)agg)[tid];
    float4 x = ((const float4*)xw)[tid];
    float4 bb = ((const float4*)b)[lane];
    float4 r;
    r.x = fmaxf(a.x + x.x * s + bb.x, 0.f);
    r.y = fmaxf(a.y + x.y * s + bb.y, 0.f);
    r.z = fmaxf(a.z + x.z * s + bb.z, 0.f);
    r.w = fmaxf(a.w + x.w * s + bb.w, 0.f);
    ((float4*)agg)[tid] = r;
}

// ---------------- pooling over sorted batch ----------------
// 64 threads/block (one per feature), each block scans a contiguous node chunk,
// flushes to pooled[] on graph change (batch is sorted -> few atomics).

__global__ void pool_kernel(const float* __restrict__ h,
                            const int* __restrict__ batch,
                            float* __restrict__ pooled,
                            int n, int chunk) {
    int f = threadIdx.x;  // 0..63
    long start = (long)blockIdx.x * chunk;
    long end = start + chunk;
    if (end > n) end = n;
    if (start >= end) return;
    int cur = batch[start];
    float acc = 0.f;
    for (long i = start; i < end; i++) {
        int g = batch[i];
        if (g != cur) {
            atomicAdd(&pooled[cur * NCLASS + f], acc);
            acc = 0.f;
            cur = g;
        }
        acc += h[i * NCLASS + f];
    }
    atomicAdd(&pooled[cur * NCLASS + f], acc);
}

// ---------------- head: MLP + log_softmax + argmax ----------------
// one block of 64 threads, thread g = graph g.

__global__ void head_kernel(const float* __restrict__ pooled,
                            const float* __restrict__ l1w,
                            const float* __restrict__ l1b,
                            const float* __restrict__ l2w,
                            const float* __restrict__ l2b,
                            float* __restrict__ out) {
    __shared__ float P[NCLASS * NUM_GRAPHS];  // transposed: P[c*64+g]
    for (int i = threadIdx.x; i < NUM_GRAPHS * NCLASS; i += 64) {
        int g = i >> 6, c = i & 63;
        P[c * 64 + g] = pooled[i];
    }
    __syncthreads();
    int g = threadIdx.x;
    float h[64];
    #pragma unroll 4
    for (int j = 0; j < 64; j++) {
        float a = l1b[j];
        for (int c = 0; c < 64; c++) a += P[c * 64 + g] * l1w[c * 64 + j];
        h[j] = fmaxf(a, 0.f);
    }
    float o0 = l2b[0], o1 = l2b[1];
    for (int j = 0; j < 64; j++) {
        o0 += h[j] * l2w[j * 2];
        o1 += h[j] * l2w[j * 2 + 1];
    }
    float m = fmaxf(o0, o1);
    float lse = m + logf(expf(o0 - m) + expf(o1 - m));
    // outputs concatenated flat: Y_prob [64,2], Y_hat [64], out [64,2]
    out[g * 2 + 0] = o0 - lse;
    out[g * 2 + 1] = o1 - lse;
    out[128 + g] = (o1 > o0) ? 1.f : 0.f;
    out[192 + g * 2 + 0] = o0;
    out[192 + g * 2 + 1] = o1;
}

// ---------------- launch ----------------

extern "C" void kernel_launch(void* const* d_in, const int* in_sizes, int n_in,
                              void* d_out, int out_size, void* d_ws, size_t ws_size,
                              hipStream_t stream) {
    const float* x   = (const float*)d_in[0];           // [N, 256]
    const int* eidx  = (const int*)d_in[1];             // [2, E] flat
    const float* ew  = (const float*)d_in[2];           // [E]
    const int* batch = (const int*)d_in[3];             // [N]
    const float* W1  = (const float*)d_in[4];           // [256,128]
    const float* b1  = (const float*)d_in[5];
    const float* W2  = (const float*)d_in[6];           // [128,64]
    const float* b2  = (const float*)d_in[7];
    const float* l1w = (const float*)d_in[8];           // [64,64]
    const float* l1b = (const float*)d_in[9];
    const float* l2w = (const float*)d_in[10];          // [64,2]
    const float* l2b = (const float*)d_in[11];
    float* out = (float*)d_out;

    const int N = N_NODES, E = N_EDGES;
    const int* rows = eidx;
    const int* cols = eidx + E;

    // workspace layout (floats)
    float* ws = (float*)d_ws;
    float* deg  = ws;                    // N
    float* dinv = ws + N;                // N
    float* bufA = ws + 200192;           // 12.8M floats (xw1; later hw2 + agg2)
    float* bufB = bufA + (long)N * NHID1;       // 12.8M floats (h1)
    float* pooled = bufB + (long)N * NHID1;     // 4096
    float* hw2  = bufA;                  // [N,64]  (reuses bufA after h1 done)
    float* agg2 = bufA + (long)N * NCLASS;      // [N,64]

    // 1. degree + norm
    init_deg_kernel<<<(N + 255) / 256, 256, 0, stream>>>(deg, N);
    deg_scatter_kernel<<<(E + 255) / 256, 256, 0, stream>>>(cols, ew, deg, E);
    dinv_kernel<<<(N + 255) / 256, 256, 0, stream>>>(deg, dinv, N);

    // 2. GEMM1: bufA = x @ W1   [N,256]@[256,128]
    {
        dim3 grid((N + 63) / 64, NHID1 / 64);
        gemm_f32_kernel<<<grid, 256, 0, stream>>>(x, W1, bufA, N, NFEAT, NHID1);
    }

    // 3. aggregate layer 1 into bufB
    hipMemsetAsync(bufB, 0, (size_t)N * NHID1 * sizeof(float), stream);
    {
        long threads = (long)E * (NHID1 / 4);
        scatter_edges_kernel<<<(threads + 255) / 256, 256, 0, stream>>>(
            bufA, rows, cols, ew, dinv, bufB, E, NHID1);
    }
    // h1 = relu(agg + xw*dinv^2 + b1), in place in bufB  (bufA free after this)
    {
        long threads = (long)N * (NHID1 / 4);
        finalize_kernel<<<(threads + 255) / 256, 256, 0, stream>>>(bufB, bufA, dinv, b1, N, NHID1);
    }

    // 4. GEMM2: hw2 = h1 @ W2   [N,128]@[128,64]
    {
        dim3 grid((N + 63) / 64, NCLASS / 64);
        gemm_f32_kernel<<<grid, 256, 0, stream>>>(bufB, W2, hw2, N, NHID1, NCLASS);
    }

    // 5. aggregate layer 2 into agg2
    hipMemsetAsync(agg2, 0, (size_t)N * NCLASS * sizeof(float), stream);
    {
        long threads = (long)E * (NCLASS / 4);
        scatter_edges_kernel<<<(threads + 255) / 256, 256, 0, stream>>>(
            hw2, rows, cols, ew, dinv, agg2, E, NCLASS);
    }
    {
        long threads = (long)N * (NCLASS / 4);
        finalize_kernel<<<(threads + 255) / 256, 256, 0, stream>>>(agg2, hw2, dinv, b2, N, NCLASS);
    }

    // 6. pool
    hipMemsetAsync(pooled, 0, NUM_GRAPHS * NCLASS * sizeof(float), stream);
    {
        int chunk = 1024;
        int blocks = (N + chunk - 1) / chunk;
        pool_kernel<<<blocks, 64, 0, stream>>>(agg2, batch, pooled, N, chunk);
    }

    // 7. head
    head_kernel<<<1, 64, 0, stream>>>(pooled, l1w, l1b, l2w, l2b, out);
}

// Round 2
// 1212.890 us; speedup vs baseline: 4.0354x; 4.0354x over previous
//
#include <hip/hip_runtime.h>
#include <hip/hip_bf16.h>
#include <math.h>

#define N_NODES 100000
#define N_EDGES 1600000
#define NFEAT 256
#define NHID1 128
#define NCLASS 64
#define NUM_GRAPHS 64

// scan geometry: 98 blocks x 1024 elems
#define SCAN_CHUNK 1024
#define SCAN_NB ((N_NODES + SCAN_CHUNK - 1) / SCAN_CHUNK)

// ---------------- degree + in-edge count (fused) ----------------

__global__ void init_deg_kernel(float* deg, int n) {
    int i = blockIdx.x * blockDim.x + threadIdx.x;
    if (i < n) deg[i] = 1.0f;  // self-loop weight
}

__global__ void count_deg_kernel(const int* __restrict__ cols,
                                 const float* __restrict__ w,
                                 int* __restrict__ cnt,
                                 float* __restrict__ deg, int nE) {
    int e = blockIdx.x * blockDim.x + threadIdx.x;
    if (e < nE) {
        int c = cols[e];
        atomicAdd(&cnt[c], 1);
        atomicAdd(&deg[c], w[e]);
    }
}

__global__ void dinv_kernel(const float* __restrict__ deg, float* __restrict__ dinv, int n) {
    int i = blockIdx.x * blockDim.x + threadIdx.x;
    if (i < n) {
        float d = deg[i];
        dinv[i] = (d > 0.f) ? rsqrtf(d) : 0.f;
    }
}

// ---------------- prefix scan (3 kernels) ----------------

__global__ __launch_bounds__(256) void scan_reduce_kernel(const int* __restrict__ cnt,
                                                          int* __restrict__ bsums, int n) {
    __shared__ int sdata[256];
    int b = blockIdx.x, t = threadIdx.x;
    int base = b * SCAN_CHUNK + t * 4;
    int s = 0;
    #pragma unroll
    for (int i = 0; i < 4; i++) {
        int idx = base + i;
        if (idx < n) s += cnt[idx];
    }
    sdata[t] = s;
    __syncthreads();
    for (int off = 128; off > 0; off >>= 1) {
        if (t < off) sdata[t] += sdata[t + off];
        __syncthreads();
    }
    if (t == 0) bsums[b] = sdata[0];
}

__global__ void scan_top_kernel(const int* __restrict__ bsums, int* __restrict__ boff, int nb) {
    if (threadIdx.x == 0 && blockIdx.x == 0) {
        int acc = 0;
        for (int i = 0; i < nb; i++) {
            boff[i] = acc;
            acc += bsums[i];
        }
    }
}

__global__ __launch_bounds__(256) void scan_final_kernel(const int* __restrict__ cnt,
                                                         const int* __restrict__ boff,
                                                         int* __restrict__ starts,
                                                         int* __restrict__ cursor, int n) {
    __shared__ int sdata[256];
    int b = blockIdx.x, t = threadIdx.x;
    int base = b * SCAN_CHUNK + t * 4;
    int v[4];
    int s = 0;
    #pragma unroll
    for (int i = 0; i < 4; i++) {
        int idx = base + i;
        v[i] = (idx < n) ? cnt[idx] : 0;
        s += v[i];
    }
    sdata[t] = s;
    __syncthreads();
    // Hillis-Steele inclusive scan over thread sums
    for (int off = 1; off < 256; off <<= 1) {
        int add = (t >= off) ? sdata[t - off] : 0;
        __syncthreads();
        sdata[t] += add;
        __syncthreads();
    }
    int texcl = sdata[t] - s + boff[b];
    int run = texcl;
    #pragma unroll
    for (int i = 0; i < 4; i++) {
        int idx = base + i;
        if (idx < n) {
            starts[idx] = run;
            cursor[idx] = run;
        }
        run += v[i];
    }
}

// ---------------- fill CSC edge arrays ----------------

__global__ void fill_kernel(const int* __restrict__ rows,
                            const int* __restrict__ cols,
                            const float* __restrict__ w,
                            const float* __restrict__ dinv,
                            int* __restrict__ cursor,
                            int* __restrict__ ssrc,
                            float* __restrict__ snorm, int nE) {
    int e = blockIdx.x * blockDim.x + threadIdx.x;
    if (e < nE) {
        int c = cols[e], r = rows[e];
        int pos = atomicAdd(&cursor[c], 1);
        ssrc[pos] = r;
        snorm[pos] = dinv[r] * w[e] * dinv[c];
    }
}

// ---------------- gather-aggregate + self-loop + bias + relu ----------------
// F/4 lanes per node, float4 accumulator in registers. No atomics.

template <int F, bool RELU>
__global__ __launch_bounds__(256) void gather_agg_kernel(const float* __restrict__ xw,
                                                         const int* __restrict__ ssrc,
                                                         const float* __restrict__ snorm,
                                                         const int* __restrict__ starts,
                                                         const int* __restrict__ cnt,
                                                         const float* __restrict__ dinv,
                                                         const float* __restrict__ bias,
                                                         float* __restrict__ out, int n) {
    constexpr int G = F / 4;  // lanes per node
    int gt = blockIdx.x * blockDim.x + threadIdx.x;
    int node = gt / G;
    int lane = gt - node * G;
    if (node >= n) return;

    int s = starts[node];
    int c = cnt[node];
    float4 acc = make_float4(0.f, 0.f, 0.f, 0.f);
    for (int j = s; j < s + c; j++) {
        int r = ssrc[j];
        float nv = snorm[j];
        float4 v = ((const float4*)(xw + (long)r * F))[lane];
        acc.x += v.x * nv;
        acc.y += v.y * nv;
        acc.z += v.z * nv;
        acc.w += v.w * nv;
    }
    // self loop: weight 1, norm = dinv[node]^2
    float d = dinv[node];
    float d2 = d * d;
    float4 sv = ((const float4*)(xw + (long)node * F))[lane];
    float4 bb = ((const float4*)bias)[lane];
    float4 r4;
    r4.x = acc.x + sv.x * d2 + bb.x;
    r4.y = acc.y + sv.y * d2 + bb.y;
    r4.z = acc.z + sv.z * d2 + bb.z;
    r4.w = acc.w + sv.w * d2 + bb.w;
    if (RELU) {
        r4.x = fmaxf(r4.x, 0.f);
        r4.y = fmaxf(r4.y, 0.f);
        r4.z = fmaxf(r4.z, 0.f);
        r4.w = fmaxf(r4.w, 0.f);
    }
    ((float4*)(out + (long)node * F))[lane] = r4;
}

// ---------------- tiled f32 GEMM: C[M,N] = A[M,K] @ B[K,N] ----------------

__global__ __launch_bounds__(256) void gemm_f32_kernel(const float* __restrict__ A,
                                                       const float* __restrict__ B,
                                                       float* __restrict__ C,
                                                       int M, int K, int N) {
    __shared__ float As[16][68];
    __shared__ float Bs[16][64];
    const int tid = threadIdx.x;
    const int tx = tid & 15;
    const int ty = tid >> 4;
    const int row0 = blockIdx.x * 64;
    const int col0 = blockIdx.y * 64;

    float acc[4][4] = {};

    for (int k0 = 0; k0 < K; k0 += 16) {
        #pragma unroll
        for (int i = 0; i < 4; i++) {
            int idx = tid + i * 256;
            int m = idx >> 4;
            int k = idx & 15;
            int gr = row0 + m;
            As[k][m] = (gr < M) ? A[(long)gr * K + k0 + k] : 0.f;
        }
        #pragma unroll
        for (int i = 0; i < 4; i++) {
            int idx = tid + i * 256;
            int k = idx >> 6;
            int n = idx & 63;
            Bs[k][n] = B[(long)(k0 + k) * N + col0 + n];
        }
        __syncthreads();
        #pragma unroll
        for (int k = 0; k < 16; k++) {
            float4 a = *(const float4*)&As[k][ty * 4];
            float4 b = *(const float4*)&Bs[k][tx * 4];
            acc[0][0] += a.x * b.x; acc[0][1] += a.x * b.y; acc[0][2] += a.x * b.z; acc[0][3] += a.x * b.w;
            acc[1][0] += a.y * b.x; acc[1][1] += a.y * b.y; acc[1][2] += a.y * b.z; acc[1][3] += a.y * b.w;
            acc[2][0] += a.z * b.x; acc[2][1] += a.z * b.y; acc[2][2] += a.z * b.z; acc[2][3] += a.z * b.w;
            acc[3][0] += a.w * b.x; acc[3][1] += a.w * b.y; acc[3][2] += a.w * b.z; acc[3][3] += a.w * b.w;
        }
        __syncthreads();
    }

    #pragma unroll
    for (int i = 0; i < 4; i++) {
        int gr = row0 + ty * 4 + i;
        if (gr < M) {
            float4 v = make_float4(acc[i][0], acc[i][1], acc[i][2], acc[i][3]);
            *(float4*)&C[(long)gr * N + col0 + tx * 4] = v;
        }
    }
}

// ---------------- pooling over sorted batch ----------------

__global__ void pool_kernel(const float* __restrict__ h,
                            const int* __restrict__ batch,
                            float* __restrict__ pooled,
                            int n, int chunk) {
    int f = threadIdx.x;  // 0..63
    long start = (long)blockIdx.x * chunk;
    long end = start + chunk;
    if (end > n) end = n;
    if (start >= end) return;
    int cur = batch[start];
    float acc = 0.f;
    for (long i = start; i < end; i++) {
        int g = batch[i];
        if (g != cur) {
            atomicAdd(&pooled[cur * NCLASS + f], acc);
            acc = 0.f;
            cur = g;
        }
        acc += h[i * NCLASS + f];
    }
    atomicAdd(&pooled[cur * NCLASS + f], acc);
}

// ---------------- head: MLP + log_softmax + argmax ----------------

__global__ void head_kernel(const float* __restrict__ pooled,
                            const float* __restrict__ l1w,
                            const float* __restrict__ l1b,
                            const float* __restrict__ l2w,
                            const float* __restrict__ l2b,
                            float* __restrict__ out) {
    __shared__ float P[NCLASS * NUM_GRAPHS];  // transposed: P[c*64+g]
    for (int i = threadIdx.x; i < NUM_GRAPHS * NCLASS; i += 64) {
        int g = i >> 6, c = i & 63;
        P[c * 64 + g] = pooled[i];
    }
    __syncthreads();
    int g = threadIdx.x;
    float h[64];
    #pragma unroll 4
    for (int j = 0; j < 64; j++) {
        float a = l1b[j];
        for (int c = 0; c < 64; c++) a += P[c * 64 + g] * l1w[c * 64 + j];
        h[j] = fmaxf(a, 0.f);
    }
    float o0 = l2b[0], o1 = l2b[1];
    for (int j = 0; j < 64; j++) {
        o0 += h[j] * l2w[j * 2];
        o1 += h[j] * l2w[j * 2 + 1];
    }
    float m = fmaxf(o0, o1);
    float lse = m + logf(expf(o0 - m) + expf(o1 - m));
    out[g * 2 + 0] = o0 - lse;
    out[g * 2 + 1] = o1 - lse;
    out[128 + g] = (o1 > o0) ? 1.f : 0.f;
    out[192 + g * 2 + 0] = o0;
    out[192 + g * 2 + 1] = o1;
}

// ---------------- launch ----------------

extern "C" void kernel_launch(void* const* d_in, const int* in_sizes, int n_in,
                              void* d_out, int out_size, void* d_ws, size_t ws_size,
                              hipStream_t stream) {
    const float* x   = (const float*)d_in[0];           // [N, 256]
    const int* eidx  = (const int*)d_in[1];             // [2, E] flat
    const float* ew  = (const float*)d_in[2];           // [E]
    const int* batch = (const int*)d_in[3];             // [N]
    const float* W1  = (const float*)d_in[4];           // [256,128]
    const float* b1  = (const float*)d_in[5];
    const float* W2  = (const float*)d_in[6];           // [128,64]
    const float* b2  = (const float*)d_in[7];
    const float* l1w = (const float*)d_in[8];           // [64,64]
    const float* l1b = (const float*)d_in[9];
    const float* l2w = (const float*)d_in[10];          // [64,2]
    const float* l2b = (const float*)d_in[11];
    float* out = (float*)d_out;

    const int N = N_NODES, E = N_EDGES;
    const int* rows = eidx;
    const int* cols = eidx + E;

    // workspace layout
    float* ws = (float*)d_ws;
    float* deg    = ws;                      // N floats
    float* dinv   = deg + N;                 // N floats
    int*   cnt    = (int*)(dinv + N);        // N ints
    int*   starts = cnt + N;                 // N ints
    int*   cursor = starts + N;              // N ints
    int*   bsums  = cursor + N;              // 256 ints
    int*   boff   = bsums + 256;             // 256 ints
    int*   ssrc   = boff + 256;              // E ints
    float* snorm  = (float*)(ssrc + E);      // E floats
    float* bufA   = snorm + E;               // N*128 floats
    float* bufB   = bufA + (long)N * NHID1;  // N*128 floats
    float* pooled = bufB + (long)N * NHID1;  // 4096 floats
    float* hw2  = bufA;                      // [N,64] reuse
    float* h2   = bufA + (long)N * NCLASS;   // [N,64] reuse

    // 1. degree + in-edge count
    init_deg_kernel<<<(N + 255) / 256, 256, 0, stream>>>(deg, N);
    hipMemsetAsync(cnt, 0, N * sizeof(int), stream);
    count_deg_kernel<<<(E + 255) / 256, 256, 0, stream>>>(cols, ew, cnt, deg, E);
    dinv_kernel<<<(N + 255) / 256, 256, 0, stream>>>(deg, dinv, N);

    // 2. prefix scan of cnt -> starts, cursor
    scan_reduce_kernel<<<SCAN_NB, 256, 0, stream>>>(cnt, bsums, N);
    scan_top_kernel<<<1, 64, 0, stream>>>(bsums, boff, SCAN_NB);
    scan_final_kernel<<<SCAN_NB, 256, 0, stream>>>(cnt, boff, starts, cursor, N);

    // 3. fill CSC (ssrc, snorm)
    fill_kernel<<<(E + 255) / 256, 256, 0, stream>>>(rows, cols, ew, dinv, cursor, ssrc, snorm, E);

    // 4. GEMM1: bufA = x @ W1   [N,256]@[256,128]
    {
        dim3 grid((N + 63) / 64, NHID1 / 64);
        gemm_f32_kernel<<<grid, 256, 0, stream>>>(x, W1, bufA, N, NFEAT, NHID1);
    }

    // 5. gather layer 1: bufB = relu(Agg(bufA) + b1)
    {
        long threads = (long)N * (NHID1 / 4);
        gather_agg_kernel<NHID1, true><<<(threads + 255) / 256, 256, 0, stream>>>(
            bufA, ssrc, snorm, starts, cnt, dinv, b1, bufB, N);
    }

    // 6. GEMM2: hw2 = h1 @ W2   [N,128]@[128,64]  (into bufA, free now)
    {
        dim3 grid((N + 63) / 64, NCLASS / 64);
        gemm_f32_kernel<<<grid, 256, 0, stream>>>(bufB, W2, hw2, N, NHID1, NCLASS);
    }

    // 7. gather layer 2: h2 = relu(Agg(hw2) + b2)
    {
        long threads = (long)N * (NCLASS / 4);
        gather_agg_kernel<NCLASS, true><<<(threads + 255) / 256, 256, 0, stream>>>(
            hw2, ssrc, snorm, starts, cnt, dinv, b2, h2, N);
    }

    // 8. pool
    hipMemsetAsync(pooled, 0, NUM_GRAPHS * NCLASS * sizeof(float), stream);
    {
        int chunk = 1024;
        int blocks = (N + chunk - 1) / chunk;
        pool_kernel<<<blocks, 64, 0, stream>>>(h2, batch, pooled, N, chunk);
    }

    // 9. head
    head_kernel<<<1, 64, 0, stream>>>(pooled, l1w, l1b, l2w, l2b, out);
}

// Round 3
// 946.263 us; speedup vs baseline: 5.1725x; 1.2818x over previous
//
#include <hip/hip_runtime.h>
#include <hip/hip_bf16.h>
#include <math.h>

#define N_NODES 100000
#define N_EDGES 1600000
#define NFEAT 256
#define NHID1 128
#define NCLASS 64
#define NUM_GRAPHS 64

// scan geometry: 98 blocks x 1024 elems
#define SCAN_CHUNK 1024
#define SCAN_NB ((N_NODES + SCAN_CHUNK - 1) / SCAN_CHUNK)

// pool geometry: small chunks for parallelism (round 3 fix: 1024 -> 64)
#define POOL_CHUNK 64

// ---------------- degree + in-edge count (fused) ----------------

__global__ void init_deg_kernel(float* deg, int n) {
    int i = blockIdx.x * blockDim.x + threadIdx.x;
    if (i < n) deg[i] = 1.0f;  // self-loop weight
}

__global__ void count_deg_kernel(const int* __restrict__ cols,
                                 const float* __restrict__ w,
                                 int* __restrict__ cnt,
                                 float* __restrict__ deg, int nE) {
    int e = blockIdx.x * blockDim.x + threadIdx.x;
    if (e < nE) {
        int c = cols[e];
        atomicAdd(&cnt[c], 1);
        atomicAdd(&deg[c], w[e]);
    }
}

__global__ void dinv_kernel(const float* __restrict__ deg, float* __restrict__ dinv, int n) {
    int i = blockIdx.x * blockDim.x + threadIdx.x;
    if (i < n) {
        float d = deg[i];
        dinv[i] = (d > 0.f) ? rsqrtf(d) : 0.f;
    }
}

// ---------------- prefix scan (3 kernels) ----------------

__global__ __launch_bounds__(256) void scan_reduce_kernel(const int* __restrict__ cnt,
                                                          int* __restrict__ bsums, int n) {
    __shared__ int sdata[256];
    int b = blockIdx.x, t = threadIdx.x;
    int base = b * SCAN_CHUNK + t * 4;
    int s = 0;
    #pragma unroll
    for (int i = 0; i < 4; i++) {
        int idx = base + i;
        if (idx < n) s += cnt[idx];
    }
    sdata[t] = s;
    __syncthreads();
    for (int off = 128; off > 0; off >>= 1) {
        if (t < off) sdata[t] += sdata[t + off];
        __syncthreads();
    }
    if (t == 0) bsums[b] = sdata[0];
}

__global__ void scan_top_kernel(const int* __restrict__ bsums, int* __restrict__ boff, int nb) {
    if (threadIdx.x == 0 && blockIdx.x == 0) {
        int acc = 0;
        for (int i = 0; i < nb; i++) {
            boff[i] = acc;
            acc += bsums[i];
        }
    }
}

__global__ __launch_bounds__(256) void scan_final_kernel(const int* __restrict__ cnt,
                                                         const int* __restrict__ boff,
                                                         int* __restrict__ starts,
                                                         int* __restrict__ cursor, int n) {
    __shared__ int sdata[256];
    int b = blockIdx.x, t = threadIdx.x;
    int base = b * SCAN_CHUNK + t * 4;
    int v[4];
    int s = 0;
    #pragma unroll
    for (int i = 0; i < 4; i++) {
        int idx = base + i;
        v[i] = (idx < n) ? cnt[idx] : 0;
        s += v[i];
    }
    sdata[t] = s;
    __syncthreads();
    // Hillis-Steele inclusive scan over thread sums
    for (int off = 1; off < 256; off <<= 1) {
        int add = (t >= off) ? sdata[t - off] : 0;
        __syncthreads();
        sdata[t] += add;
        __syncthreads();
    }
    int texcl = sdata[t] - s + boff[b];
    int run = texcl;
    #pragma unroll
    for (int i = 0; i < 4; i++) {
        int idx = base + i;
        if (idx < n) {
            starts[idx] = run;
            cursor[idx] = run;
        }
        run += v[i];
    }
}

// ---------------- fill CSC edge arrays ----------------

__global__ void fill_kernel(const int* __restrict__ rows,
                            const int* __restrict__ cols,
                            const float* __restrict__ w,
                            const float* __restrict__ dinv,
                            int* __restrict__ cursor,
                            int* __restrict__ ssrc,
                            float* __restrict__ snorm, int nE) {
    int e = blockIdx.x * blockDim.x + threadIdx.x;
    if (e < nE) {
        int c = cols[e], r = rows[e];
        int pos = atomicAdd(&cursor[c], 1);
        ssrc[pos] = r;
        snorm[pos] = dinv[r] * w[e] * dinv[c];
    }
}

// ---------------- gather-aggregate + self-loop + bias + relu ----------------
// F/4 lanes per node, float4 accumulator in registers. No atomics.

template <int F, bool RELU>
__global__ __launch_bounds__(256) void gather_agg_kernel(const float* __restrict__ xw,
                                                         const int* __restrict__ ssrc,
                                                         const float* __restrict__ snorm,
                                                         const int* __restrict__ starts,
                                                         const int* __restrict__ cnt,
                                                         const float* __restrict__ dinv,
                                                         const float* __restrict__ bias,
                                                         float* __restrict__ out, int n) {
    constexpr int G = F / 4;  // lanes per node
    int gt = blockIdx.x * blockDim.x + threadIdx.x;
    int node = gt / G;
    int lane = gt - node * G;
    if (node >= n) return;

    int s = starts[node];
    int c = cnt[node];
    float4 acc = make_float4(0.f, 0.f, 0.f, 0.f);
    for (int j = s; j < s + c; j++) {
        int r = ssrc[j];
        float nv = snorm[j];
        float4 v = ((const float4*)(xw + (long)r * F))[lane];
        acc.x += v.x * nv;
        acc.y += v.y * nv;
        acc.z += v.z * nv;
        acc.w += v.w * nv;
    }
    // self loop: weight 1, norm = dinv[node]^2
    float d = dinv[node];
    float d2 = d * d;
    float4 sv = ((const float4*)(xw + (long)node * F))[lane];
    float4 bb = ((const float4*)bias)[lane];
    float4 r4;
    r4.x = acc.x + sv.x * d2 + bb.x;
    r4.y = acc.y + sv.y * d2 + bb.y;
    r4.z = acc.z + sv.z * d2 + bb.z;
    r4.w = acc.w + sv.w * d2 + bb.w;
    if (RELU) {
        r4.x = fmaxf(r4.x, 0.f);
        r4.y = fmaxf(r4.y, 0.f);
        r4.z = fmaxf(r4.z, 0.f);
        r4.w = fmaxf(r4.w, 0.f);
    }
    ((float4*)(out + (long)node * F))[lane] = r4;
}

// ---------------- tiled f32 GEMM: C[M,N] = A[M,K] @ B[K,N] ----------------

__global__ __launch_bounds__(256) void gemm_f32_kernel(const float* __restrict__ A,
                                                       const float* __restrict__ B,
                                                       float* __restrict__ C,
                                                       int M, int K, int N) {
    __shared__ float As[16][68];
    __shared__ float Bs[16][64];
    const int tid = threadIdx.x;
    const int tx = tid & 15;
    const int ty = tid >> 4;
    const int row0 = blockIdx.x * 64;
    const int col0 = blockIdx.y * 64;

    float acc[4][4] = {};

    for (int k0 = 0; k0 < K; k0 += 16) {
        #pragma unroll
        for (int i = 0; i < 4; i++) {
            int idx = tid + i * 256;
            int m = idx >> 4;
            int k = idx & 15;
            int gr = row0 + m;
            As[k][m] = (gr < M) ? A[(long)gr * K + k0 + k] : 0.f;
        }
        #pragma unroll
        for (int i = 0; i < 4; i++) {
            int idx = tid + i * 256;
            int k = idx >> 6;
            int n = idx & 63;
            Bs[k][n] = B[(long)(k0 + k) * N + col0 + n];
        }
        __syncthreads();
        #pragma unroll
        for (int k = 0; k < 16; k++) {
            float4 a = *(const float4*)&As[k][ty * 4];
            float4 b = *(const float4*)&Bs[k][tx * 4];
            acc[0][0] += a.x * b.x; acc[0][1] += a.x * b.y; acc[0][2] += a.x * b.z; acc[0][3] += a.x * b.w;
            acc[1][0] += a.y * b.x; acc[1][1] += a.y * b.y; acc[1][2] += a.y * b.z; acc[1][3] += a.y * b.w;
            acc[2][0] += a.z * b.x; acc[2][1] += a.z * b.y; acc[2][2] += a.z * b.z; acc[2][3] += a.z * b.w;
            acc[3][0] += a.w * b.x; acc[3][1] += a.w * b.y; acc[3][2] += a.w * b.z; acc[3][3] += a.w * b.w;
        }
        __syncthreads();
    }

    #pragma unroll
    for (int i = 0; i < 4; i++) {
        int gr = row0 + ty * 4 + i;
        if (gr < M) {
            float4 v = make_float4(acc[i][0], acc[i][1], acc[i][2], acc[i][3]);
            *(float4*)&C[(long)gr * N + col0 + tx * 4] = v;
        }
    }
}

// ---------------- pooling over sorted batch ----------------
// 64 threads/block (one per feature), each block scans POOL_CHUNK nodes,
// flushes to pooled[] on graph change (batch is sorted -> few atomics).
// chunk=64 -> 1563 blocks (~6 waves/CU) vs the old 98-block launch.

__global__ void pool_kernel(const float* __restrict__ h,
                            const int* __restrict__ batch,
                            float* __restrict__ pooled,
                            int n) {
    int f = threadIdx.x;  // 0..63
    long start = (long)blockIdx.x * POOL_CHUNK;
    long end = start + POOL_CHUNK;
    if (end > n) end = n;
    if (start >= end) return;
    int cur = batch[start];
    float acc = 0.f;
    for (long i = start; i < end; i++) {
        int g = batch[i];
        if (g != cur) {
            atomicAdd(&pooled[cur * NCLASS + f], acc);
            acc = 0.f;
            cur = g;
        }
        acc += h[i * NCLASS + f];
    }
    atomicAdd(&pooled[cur * NCLASS + f], acc);
}

// ---------------- head: MLP + log_softmax + argmax ----------------

__global__ void head_kernel(const float* __restrict__ pooled,
                            const float* __restrict__ l1w,
                            const float* __restrict__ l1b,
                            const float* __restrict__ l2w,
                            const float* __restrict__ l2b,
                            float* __restrict__ out) {
    __shared__ float P[NCLASS * NUM_GRAPHS];  // transposed: P[c*64+g]
    for (int i = threadIdx.x; i < NUM_GRAPHS * NCLASS; i += 64) {
        int g = i >> 6, c = i & 63;
        P[c * 64 + g] = pooled[i];
    }
    __syncthreads();
    int g = threadIdx.x;
    float h[64];
    #pragma unroll 4
    for (int j = 0; j < 64; j++) {
        float a = l1b[j];
        for (int c = 0; c < 64; c++) a += P[c * 64 + g] * l1w[c * 64 + j];
        h[j] = fmaxf(a, 0.f);
    }
    float o0 = l2b[0], o1 = l2b[1];
    for (int j = 0; j < 64; j++) {
        o0 += h[j] * l2w[j * 2];
        o1 += h[j] * l2w[j * 2 + 1];
    }
    float m = fmaxf(o0, o1);
    float lse = m + logf(expf(o0 - m) + expf(o1 - m));
    out[g * 2 + 0] = o0 - lse;
    out[g * 2 + 1] = o1 - lse;
    out[128 + g] = (o1 > o0) ? 1.f : 0.f;
    out[192 + g * 2 + 0] = o0;
    out[192 + g * 2 + 1] = o1;
}

// ---------------- launch ----------------

extern "C" void kernel_launch(void* const* d_in, const int* in_sizes, int n_in,
                              void* d_out, int out_size, void* d_ws, size_t ws_size,
                              hipStream_t stream) {
    const float* x   = (const float*)d_in[0];           // [N, 256]
    const int* eidx  = (const int*)d_in[1];             // [2, E] flat
    const float* ew  = (const float*)d_in[2];           // [E]
    const int* batch = (const int*)d_in[3];             // [N]
    const float* W1  = (const float*)d_in[4];           // [256,128]
    const float* b1  = (const float*)d_in[5];
    const float* W2  = (const float*)d_in[6];           // [128,64]
    const float* b2  = (const float*)d_in[7];
    const float* l1w = (const float*)d_in[8];           // [64,64]
    const float* l1b = (const float*)d_in[9];
    const float* l2w = (const float*)d_in[10];          // [64,2]
    const float* l2b = (const float*)d_in[11];
    float* out = (float*)d_out;

    const int N = N_NODES, E = N_EDGES;
    const int* rows = eidx;
    const int* cols = eidx + E;

    // workspace layout
    float* ws = (float*)d_ws;
    float* deg    = ws;                      // N floats
    float* dinv   = deg + N;                 // N floats
    int*   cnt    = (int*)(dinv + N);        // N ints
    int*   starts = cnt + N;                 // N ints
    int*   cursor = starts + N;              // N ints
    int*   bsums  = cursor + N;              // 256 ints
    int*   boff   = bsums + 256;             // 256 ints
    int*   ssrc   = boff + 256;              // E ints
    float* snorm  = (float*)(ssrc + E);      // E floats
    float* bufA   = snorm + E;               // N*128 floats
    float* bufB   = bufA + (long)N * NHID1;  // N*128 floats
    float* pooled = bufB + (long)N * NHID1;  // 4096 floats
    float* hw2  = bufA;                      // [N,64] reuse
    float* h2   = bufA + (long)N * NCLASS;   // [N,64] reuse

    // 1. degree + in-edge count
    init_deg_kernel<<<(N + 255) / 256, 256, 0, stream>>>(deg, N);
    hipMemsetAsync(cnt, 0, N * sizeof(int), stream);
    count_deg_kernel<<<(E + 255) / 256, 256, 0, stream>>>(cols, ew, cnt, deg, E);
    dinv_kernel<<<(N + 255) / 256, 256, 0, stream>>>(deg, dinv, N);

    // 2. prefix scan of cnt -> starts, cursor
    scan_reduce_kernel<<<SCAN_NB, 256, 0, stream>>>(cnt, bsums, N);
    scan_top_kernel<<<1, 64, 0, stream>>>(bsums, boff, SCAN_NB);
    scan_final_kernel<<<SCAN_NB, 256, 0, stream>>>(cnt, boff, starts, cursor, N);

    // 3. fill CSC (ssrc, snorm)
    fill_kernel<<<(E + 255) / 256, 256, 0, stream>>>(rows, cols, ew, dinv, cursor, ssrc, snorm, E);

    // 4. GEMM1: bufA = x @ W1   [N,256]@[256,128]
    {
        dim3 grid((N + 63) / 64, NHID1 / 64);
        gemm_f32_kernel<<<grid, 256, 0, stream>>>(x, W1, bufA, N, NFEAT, NHID1);
    }

    // 5. gather layer 1: bufB = relu(Agg(bufA) + b1)
    {
        long threads = (long)N * (NHID1 / 4);
        gather_agg_kernel<NHID1, true><<<(threads + 255) / 256, 256, 0, stream>>>(
            bufA, ssrc, snorm, starts, cnt, dinv, b1, bufB, N);
    }

    // 6. GEMM2: hw2 = h1 @ W2   [N,128]@[128,64]  (into bufA, free now)
    {
        dim3 grid((N + 63) / 64, NCLASS / 64);
        gemm_f32_kernel<<<grid, 256, 0, stream>>>(bufB, W2, hw2, N, NHID1, NCLASS);
    }

    // 7. gather layer 2: h2 = relu(Agg(hw2) + b2)
    {
        long threads = (long)N * (NCLASS / 4);
        gather_agg_kernel<NCLASS, true><<<(threads + 255) / 256, 256, 0, stream>>>(
            hw2, ssrc, snorm, starts, cnt, dinv, b2, h2, N);
    }

    // 8. pool
    hipMemsetAsync(pooled, 0, NUM_GRAPHS * NCLASS * sizeof(float), stream);
    {
        int blocks = (N + POOL_CHUNK - 1) / POOL_CHUNK;
        pool_kernel<<<blocks, 64, 0, stream>>>(h2, batch, pooled, N);
    }

    // 9. head
    head_kernel<<<1, 64, 0, stream>>>(pooled, l1w, l1b, l2w, l2b, out);
}

// Round 4
// 908.614 us; speedup vs baseline: 5.3868x; 1.0414x over previous
//
#include <hip/hip_runtime.h>
#include <hip/hip_bf16.h>
#include <math.h>

#define N_NODES 100000
#define N_EDGES 1600000
#define NFEAT 256
#define NHID1 128
#define NCLASS 64
#define NUM_GRAPHS 64

// scan geometry: 98 blocks x 1024 elems
#define SCAN_CHUNK 1024
#define SCAN_NB ((N_NODES + SCAN_CHUNK - 1) / SCAN_CHUNK)

// pool geometry: small chunks for parallelism
#define POOL_CHUNK 64

// ---------------- degree + in-edge count (fused) ----------------

__global__ void init_deg_kernel(float* deg, int n) {
    int i = blockIdx.x * blockDim.x + threadIdx.x;
    if (i < n) deg[i] = 1.0f;  // self-loop weight
}

__global__ void count_deg_kernel(const int* __restrict__ cols,
                                 const float* __restrict__ w,
                                 int* __restrict__ cnt,
                                 float* __restrict__ deg, int nE) {
    int e = blockIdx.x * blockDim.x + threadIdx.x;
    if (e < nE) {
        int c = cols[e];
        atomicAdd(&cnt[c], 1);
        atomicAdd(&deg[c], w[e]);
    }
}

__global__ void dinv_kernel(const float* __restrict__ deg, float* __restrict__ dinv, int n) {
    int i = blockIdx.x * blockDim.x + threadIdx.x;
    if (i < n) {
        float d = deg[i];
        dinv[i] = (d > 0.f) ? rsqrtf(d) : 0.f;
    }
}

// ---------------- prefix scan (3 kernels) ----------------

__global__ __launch_bounds__(256) void scan_reduce_kernel(const int* __restrict__ cnt,
                                                          int* __restrict__ bsums, int n) {
    __shared__ int sdata[256];
    int b = blockIdx.x, t = threadIdx.x;
    int base = b * SCAN_CHUNK + t * 4;
    int s = 0;
    #pragma unroll
    for (int i = 0; i < 4; i++) {
        int idx = base + i;
        if (idx < n) s += cnt[idx];
    }
    sdata[t] = s;
    __syncthreads();
    for (int off = 128; off > 0; off >>= 1) {
        if (t < off) sdata[t] += sdata[t + off];
        __syncthreads();
    }
    if (t == 0) bsums[b] = sdata[0];
}

__global__ void scan_top_kernel(const int* __restrict__ bsums, int* __restrict__ boff, int nb) {
    if (threadIdx.x == 0 && blockIdx.x == 0) {
        int acc = 0;
        for (int i = 0; i < nb; i++) {
            boff[i] = acc;
            acc += bsums[i];
        }
    }
}

__global__ __launch_bounds__(256) void scan_final_kernel(const int* __restrict__ cnt,
                                                         const int* __restrict__ boff,
                                                         int* __restrict__ starts,
                                                         int* __restrict__ cursor, int n) {
    __shared__ int sdata[256];
    int b = blockIdx.x, t = threadIdx.x;
    int base = b * SCAN_CHUNK + t * 4;
    int v[4];
    int s = 0;
    #pragma unroll
    for (int i = 0; i < 4; i++) {
        int idx = base + i;
        v[i] = (idx < n) ? cnt[idx] : 0;
        s += v[i];
    }
    sdata[t] = s;
    __syncthreads();
    // Hillis-Steele inclusive scan over thread sums
    for (int off = 1; off < 256; off <<= 1) {
        int add = (t >= off) ? sdata[t - off] : 0;
        __syncthreads();
        sdata[t] += add;
        __syncthreads();
    }
    int texcl = sdata[t] - s + boff[b];
    int run = texcl;
    #pragma unroll
    for (int i = 0; i < 4; i++) {
        int idx = base + i;
        if (idx < n) {
            starts[idx] = run;
            cursor[idx] = run;
        }
        run += v[i];
    }
}

// ---------------- fill CSC edge arrays ----------------

__global__ void fill_kernel(const int* __restrict__ rows,
                            const int* __restrict__ cols,
                            const float* __restrict__ w,
                            const float* __restrict__ dinv,
                            int* __restrict__ cursor,
                            int* __restrict__ ssrc,
                            float* __restrict__ snorm, int nE) {
    int e = blockIdx.x * blockDim.x + threadIdx.x;
    if (e < nE) {
        int c = cols[e], r = rows[e];
        int pos = atomicAdd(&cursor[c], 1);
        ssrc[pos] = r;
        snorm[pos] = dinv[r] * w[e] * dinv[c];
    }
}

// ---------------- gather-aggregate + self-loop + bias + relu ----------------

template <int F, bool RELU>
__global__ __launch_bounds__(256) void gather_agg_kernel(const float* __restrict__ xw,
                                                         const int* __restrict__ ssrc,
                                                         const float* __restrict__ snorm,
                                                         const int* __restrict__ starts,
                                                         const int* __restrict__ cnt,
                                                         const float* __restrict__ dinv,
                                                         const float* __restrict__ bias,
                                                         float* __restrict__ out, int n) {
    constexpr int G = F / 4;  // lanes per node
    int gt = blockIdx.x * blockDim.x + threadIdx.x;
    int node = gt / G;
    int lane = gt - node * G;
    if (node >= n) return;

    int s = starts[node];
    int c = cnt[node];
    float4 acc = make_float4(0.f, 0.f, 0.f, 0.f);
    for (int j = s; j < s + c; j++) {
        int r = ssrc[j];
        float nv = snorm[j];
        float4 v = ((const float4*)(xw + (long)r * F))[lane];
        acc.x += v.x * nv;
        acc.y += v.y * nv;
        acc.z += v.z * nv;
        acc.w += v.w * nv;
    }
    // self loop: weight 1, norm = dinv[node]^2
    float d = dinv[node];
    float d2 = d * d;
    float4 sv = ((const float4*)(xw + (long)node * F))[lane];
    float4 bb = ((const float4*)bias)[lane];
    float4 r4;
    r4.x = acc.x + sv.x * d2 + bb.x;
    r4.y = acc.y + sv.y * d2 + bb.y;
    r4.z = acc.z + sv.z * d2 + bb.z;
    r4.w = acc.w + sv.w * d2 + bb.w;
    if (RELU) {
        r4.x = fmaxf(r4.x, 0.f);
        r4.y = fmaxf(r4.y, 0.f);
        r4.z = fmaxf(r4.z, 0.f);
        r4.w = fmaxf(r4.w, 0.f);
    }
    ((float4*)(out + (long)node * F))[lane] = r4;
}

// ---------------- f32 GEMM v2: 128xNT tile, 8x8 (or 8x4) microtile ----------------
// CG = column groups of 64; NT = CG*64. 256 threads.
// Microtile: rows {ty*4..+3} U {64+ty*4..+3}, cols per group {tx*4..+3}+g*64.
// All LDS compute accesses are broadcast or 2-way (free). A staged transposed.

template <int CG>
__global__ __launch_bounds__(256, 2) void gemm_f32_v2(const float* __restrict__ A,
                                                      const float* __restrict__ B,
                                                      float* __restrict__ C,
                                                      int M, int K, int N) {
    constexpr int NT = CG * 64;
    __shared__ float As[16][132];       // transposed A tile [k][row], pad 132
    __shared__ float Bs[16][NT + 4];    // B tile [k][col]
    const int tid = threadIdx.x;
    const int tx = tid & 15;
    const int ty = tid >> 4;
    const int row0 = blockIdx.x * 128;
    const int col0 = blockIdx.y * NT;

    float acc[2][CG][4][4] = {};

    // staging indices
    const int arow = tid >> 1;          // 0..127
    const int akc  = (tid & 1) * 8;     // 0 or 8
    const int bk   = tid >> 4;          // 0..15
    const int bn   = tx * (CG == 2 ? 8 : 4);

    const int agr = row0 + arow;
    const float* aptr = A + (long)agr * K + akc;
    const float* bptr = B + (long)bk * N + col0 + bn;

    for (int k0 = 0; k0 < K; k0 += 16) {
        // stage A (transposed): 2 float4 along K -> 8 scattered f32 (2-way banks, free)
        float4 a0 = make_float4(0.f, 0.f, 0.f, 0.f), a1 = a0;
        if (agr < M) {
            a0 = *(const float4*)(aptr + k0);
            a1 = *(const float4*)(aptr + k0 + 4);
        }
        As[akc + 0][arow] = a0.x;
        As[akc + 1][arow] = a0.y;
        As[akc + 2][arow] = a0.z;
        As[akc + 3][arow] = a0.w;
        As[akc + 4][arow] = a1.x;
        As[akc + 5][arow] = a1.y;
        As[akc + 6][arow] = a1.z;
        As[akc + 7][arow] = a1.w;
        // stage B
        {
            const float* bp = bptr + (long)k0 * N;
            if (CG == 2) {
                *(float4*)&Bs[bk][bn]     = *(const float4*)bp;
                *(float4*)&Bs[bk][bn + 4] = *(const float4*)(bp + 4);
            } else {
                *(float4*)&Bs[bk][bn] = *(const float4*)bp;
            }
        }
        __syncthreads();

        #pragma unroll
        for (int k = 0; k < 16; k++) {
            float av[2][4], bv[CG][4];
            *(float4*)av[0] = *(const float4*)&As[k][ty * 4];
            *(float4*)av[1] = *(const float4*)&As[k][64 + ty * 4];
            #pragma unroll
            for (int g = 0; g < CG; g++)
                *(float4*)bv[g] = *(const float4*)&Bs[k][g * 64 + tx * 4];
            #pragma unroll
            for (int rg = 0; rg < 2; rg++)
                #pragma unroll
                for (int g = 0; g < CG; g++)
                    #pragma unroll
                    for (int i = 0; i < 4; i++)
                        #pragma unroll
                        for (int j = 0; j < 4; j++)
                            acc[rg][g][i][j] += av[rg][i] * bv[g][j];
        }
        __syncthreads();
    }

    #pragma unroll
    for (int rg = 0; rg < 2; rg++) {
        #pragma unroll
        for (int i = 0; i < 4; i++) {
            int gr = row0 + rg * 64 + ty * 4 + i;
            if (gr < M) {
                #pragma unroll
                for (int g = 0; g < CG; g++) {
                    float4 v = make_float4(acc[rg][g][i][0], acc[rg][g][i][1],
                                           acc[rg][g][i][2], acc[rg][g][i][3]);
                    *(float4*)&C[(long)gr * N + col0 + g * 64 + tx * 4] = v;
                }
            }
        }
    }
}

// ---------------- pooling over sorted batch ----------------

__global__ void pool_kernel(const float* __restrict__ h,
                            const int* __restrict__ batch,
                            float* __restrict__ pooled,
                            int n) {
    int f = threadIdx.x;  // 0..63
    long start = (long)blockIdx.x * POOL_CHUNK;
    long end = start + POOL_CHUNK;
    if (end > n) end = n;
    if (start >= end) return;
    int cur = batch[start];
    float acc = 0.f;
    for (long i = start; i < end; i++) {
        int g = batch[i];
        if (g != cur) {
            atomicAdd(&pooled[cur * NCLASS + f], acc);
            acc = 0.f;
            cur = g;
        }
        acc += h[i * NCLASS + f];
    }
    atomicAdd(&pooled[cur * NCLASS + f], acc);
}

// ---------------- head: MLP + log_softmax + argmax ----------------

__global__ void head_kernel(const float* __restrict__ pooled,
                            const float* __restrict__ l1w,
                            const float* __restrict__ l1b,
                            const float* __restrict__ l2w,
                            const float* __restrict__ l2b,
                            float* __restrict__ out) {
    __shared__ float P[NCLASS * NUM_GRAPHS];  // transposed: P[c*64+g]
    for (int i = threadIdx.x; i < NUM_GRAPHS * NCLASS; i += 64) {
        int g = i >> 6, c = i & 63;
        P[c * 64 + g] = pooled[i];
    }
    __syncthreads();
    int g = threadIdx.x;
    float h[64];
    #pragma unroll 4
    for (int j = 0; j < 64; j++) {
        float a = l1b[j];
        for (int c = 0; c < 64; c++) a += P[c * 64 + g] * l1w[c * 64 + j];
        h[j] = fmaxf(a, 0.f);
    }
    float o0 = l2b[0], o1 = l2b[1];
    for (int j = 0; j < 64; j++) {
        o0 += h[j] * l2w[j * 2];
        o1 += h[j] * l2w[j * 2 + 1];
    }
    float m = fmaxf(o0, o1);
    float lse = m + logf(expf(o0 - m) + expf(o1 - m));
    out[g * 2 + 0] = o0 - lse;
    out[g * 2 + 1] = o1 - lse;
    out[128 + g] = (o1 > o0) ? 1.f : 0.f;
    out[192 + g * 2 + 0] = o0;
    out[192 + g * 2 + 1] = o1;
}

// ---------------- launch ----------------

extern "C" void kernel_launch(void* const* d_in, const int* in_sizes, int n_in,
                              void* d_out, int out_size, void* d_ws, size_t ws_size,
                              hipStream_t stream) {
    const float* x   = (const float*)d_in[0];           // [N, 256]
    const int* eidx  = (const int*)d_in[1];             // [2, E] flat
    const float* ew  = (const float*)d_in[2];           // [E]
    const int* batch = (const int*)d_in[3];             // [N]
    const float* W1  = (const float*)d_in[4];           // [256,128]
    const float* b1  = (const float*)d_in[5];
    const float* W2  = (const float*)d_in[6];           // [128,64]
    const float* b2  = (const float*)d_in[7];
    const float* l1w = (const float*)d_in[8];           // [64,64]
    const float* l1b = (const float*)d_in[9];
    const float* l2w = (const float*)d_in[10];          // [64,2]
    const float* l2b = (const float*)d_in[11];
    float* out = (float*)d_out;

    const int N = N_NODES, E = N_EDGES;
    const int* rows = eidx;
    const int* cols = eidx + E;

    // workspace layout
    float* ws = (float*)d_ws;
    float* deg    = ws;                      // N floats
    float* dinv   = deg + N;                 // N floats
    int*   cnt    = (int*)(dinv + N);        // N ints
    int*   starts = cnt + N;                 // N ints
    int*   cursor = starts + N;              // N ints
    int*   bsums  = cursor + N;              // 256 ints
    int*   boff   = bsums + 256;             // 256 ints
    int*   ssrc   = boff + 256;              // E ints
    float* snorm  = (float*)(ssrc + E);      // E floats
    float* bufA   = snorm + E;               // N*128 floats
    float* bufB   = bufA + (long)N * NHID1;  // N*128 floats
    float* pooled = bufB + (long)N * NHID1;  // 4096 floats
    float* hw2  = bufA;                      // [N,64] reuse
    float* h2   = bufA + (long)N * NCLASS;   // [N,64] reuse

    // 1. degree + in-edge count
    init_deg_kernel<<<(N + 255) / 256, 256, 0, stream>>>(deg, N);
    hipMemsetAsync(cnt, 0, N * sizeof(int), stream);
    count_deg_kernel<<<(E + 255) / 256, 256, 0, stream>>>(cols, ew, cnt, deg, E);
    dinv_kernel<<<(N + 255) / 256, 256, 0, stream>>>(deg, dinv, N);

    // 2. prefix scan of cnt -> starts, cursor
    scan_reduce_kernel<<<SCAN_NB, 256, 0, stream>>>(cnt, bsums, N);
    scan_top_kernel<<<1, 64, 0, stream>>>(bsums, boff, SCAN_NB);
    scan_final_kernel<<<SCAN_NB, 256, 0, stream>>>(cnt, boff, starts, cursor, N);

    // 3. fill CSC (ssrc, snorm)
    fill_kernel<<<(E + 255) / 256, 256, 0, stream>>>(rows, cols, ew, dinv, cursor, ssrc, snorm, E);

    // 4. GEMM1: bufA = x @ W1   [N,256]@[256,128]  (128x128 tile)
    {
        dim3 grid((N + 127) / 128, NHID1 / 128);
        gemm_f32_v2<2><<<grid, 256, 0, stream>>>(x, W1, bufA, N, NFEAT, NHID1);
    }

    // 5. gather layer 1: bufB = relu(Agg(bufA) + b1)
    {
        long threads = (long)N * (NHID1 / 4);
        gather_agg_kernel<NHID1, true><<<(threads + 255) / 256, 256, 0, stream>>>(
            bufA, ssrc, snorm, starts, cnt, dinv, b1, bufB, N);
    }

    // 6. GEMM2: hw2 = h1 @ W2   [N,128]@[128,64]  (128x64 tile)
    {
        dim3 grid((N + 127) / 128, NCLASS / 64);
        gemm_f32_v2<1><<<grid, 256, 0, stream>>>(bufB, W2, hw2, N, NHID1, NCLASS);
    }

    // 7. gather layer 2: h2 = relu(Agg(hw2) + b2)
    {
        long threads = (long)N * (NCLASS / 4);
        gather_agg_kernel<NCLASS, true><<<(threads + 255) / 256, 256, 0, stream>>>(
            hw2, ssrc, snorm, starts, cnt, dinv, b2, h2, N);
    }

    // 8. pool
    hipMemsetAsync(pooled, 0, NUM_GRAPHS * NCLASS * sizeof(float), stream);
    {
        int blocks = (N + POOL_CHUNK - 1) / POOL_CHUNK;
        pool_kernel<<<blocks, 64, 0, stream>>>(h2, batch, pooled, N);
    }

    // 9. head
    head_kernel<<<1, 64, 0, stream>>>(pooled, l1w, l1b, l2w, l2b, out);
}

// Round 5
// 812.835 us; speedup vs baseline: 6.0216x; 1.1178x over previous
//
#include <hip/hip_runtime.h>
#include <hip/hip_bf16.h>
#include <math.h>

#define N_NODES 100000
#define N_EDGES 1600000
#define NFEAT 256
#define NHID1 128
#define NCLASS 64
#define NUM_GRAPHS 64

// scan geometry: 98 blocks x 1024 elems
#define SCAN_CHUNK 1024
#define SCAN_NB ((N_NODES + SCAN_CHUNK - 1) / SCAN_CHUNK)

// pool geometry
#define POOL_CHUNK 64

// ---------------- pass 1: packed count+degree (ONE u64 atomic per edge) ----------------
// packed[c] bits 52..63 = in-edge count, bits 0..51 = sum(w) in 2^-32 fixed point.

__global__ void count_deg_kernel(const int* __restrict__ cols,
                                 const float* __restrict__ w,
                                 unsigned long long* __restrict__ packed, int nE) {
    int e = blockIdx.x * blockDim.x + threadIdx.x;
    if (e < nE) {
        int c = cols[e];
        unsigned long long fix = (unsigned long long)((double)w[e] * 4294967296.0 + 0.5);
        atomicAdd(&packed[c], (1ULL << 52) | fix);
    }
}

// decode: cnt + dinv (deg = 1 + sum(w), self-loop included)
__global__ void decode_kernel(const unsigned long long* __restrict__ packed,
                              int* __restrict__ cnt,
                              float* __restrict__ dinv, int n) {
    int i = blockIdx.x * blockDim.x + threadIdx.x;
    if (i < n) {
        unsigned long long p = packed[i];
        cnt[i] = (int)(p >> 52);
        double degw = (double)(p & ((1ULL << 52) - 1)) * (1.0 / 4294967296.0);
        float deg = (float)(1.0 + degw);
        dinv[i] = rsqrtf(deg);
    }
}

// ---------------- prefix scan (3 kernels) ----------------

__global__ __launch_bounds__(256) void scan_reduce_kernel(const int* __restrict__ cnt,
                                                          int* __restrict__ bsums, int n) {
    __shared__ int sdata[256];
    int b = blockIdx.x, t = threadIdx.x;
    int base = b * SCAN_CHUNK + t * 4;
    int s = 0;
    #pragma unroll
    for (int i = 0; i < 4; i++) {
        int idx = base + i;
        if (idx < n) s += cnt[idx];
    }
    sdata[t] = s;
    __syncthreads();
    for (int off = 128; off > 0; off >>= 1) {
        if (t < off) sdata[t] += sdata[t + off];
        __syncthreads();
    }
    if (t == 0) bsums[b] = sdata[0];
}

__global__ void scan_top_kernel(const int* __restrict__ bsums, int* __restrict__ boff, int nb) {
    if (threadIdx.x == 0 && blockIdx.x == 0) {
        int acc = 0;
        for (int i = 0; i < nb; i++) {
            boff[i] = acc;
            acc += bsums[i];
        }
    }
}

__global__ __launch_bounds__(256) void scan_final_kernel(const int* __restrict__ cnt,
                                                         const int* __restrict__ boff,
                                                         int* __restrict__ starts,
                                                         int* __restrict__ cursor, int n) {
    __shared__ int sdata[256];
    int b = blockIdx.x, t = threadIdx.x;
    int base = b * SCAN_CHUNK + t * 4;
    int v[4];
    int s = 0;
    #pragma unroll
    for (int i = 0; i < 4; i++) {
        int idx = base + i;
        v[i] = (idx < n) ? cnt[idx] : 0;
        s += v[i];
    }
    sdata[t] = s;
    __syncthreads();
    for (int off = 1; off < 256; off <<= 1) {
        int add = (t >= off) ? sdata[t - off] : 0;
        __syncthreads();
        sdata[t] += add;
        __syncthreads();
    }
    int run = sdata[t] - s + boff[b];
    #pragma unroll
    for (int i = 0; i < 4; i++) {
        int idx = base + i;
        if (idx < n) {
            starts[idx] = run;
            cursor[idx] = run;
        }
        run += v[i];
    }
}

// ---------------- fill CSC: one 8B store per edge ----------------

__global__ void fill_kernel(const int* __restrict__ rows,
                            const int* __restrict__ cols,
                            const float* __restrict__ w,
                            int* __restrict__ cursor,
                            int2* __restrict__ edges, int nE) {
    int e = blockIdx.x * blockDim.x + threadIdx.x;
    if (e < nE) {
        int c = cols[e], r = rows[e];
        int pos = atomicAdd(&cursor[c], 1);
        edges[pos] = make_int2(r, __float_as_int(w[e]));
    }
}

// ---------------- gather-aggregate (dinv pre-folded into features) ----------------
// xs[i] = (x@W)[i] * dinv[i].  out[c] = relu(dinv[c]*(sum_e w_e*xs[r_e] + xs[c]) + b)

template <int F, bool RELU>
__global__ __launch_bounds__(256) void gather_agg_kernel(const float* __restrict__ xs,
                                                         const int2* __restrict__ edges,
                                                         const int* __restrict__ starts,
                                                         const int* __restrict__ cnt,
                                                         const float* __restrict__ dinv,
                                                         const float* __restrict__ bias,
                                                         float* __restrict__ out, int n) {
    constexpr int G = F / 4;  // lanes per node
    int gt = blockIdx.x * blockDim.x + threadIdx.x;
    int node = gt / G;
    int lane = gt - node * G;
    if (node >= n) return;

    int s = starts[node];
    int c = cnt[node];
    float4 acc = make_float4(0.f, 0.f, 0.f, 0.f);
    for (int j = s; j < s + c; j++) {
        int2 ed = edges[j];
        float wv = __int_as_float(ed.y);
        float4 v = ((const float4*)(xs + (long)ed.x * F))[lane];
        acc.x += v.x * wv;
        acc.y += v.y * wv;
        acc.z += v.z * wv;
        acc.w += v.w * wv;
    }
    float d = dinv[node];
    float4 sv = ((const float4*)(xs + (long)node * F))[lane];
    float4 bb = ((const float4*)bias)[lane];
    float4 r4;
    r4.x = d * (acc.x + sv.x) + bb.x;
    r4.y = d * (acc.y + sv.y) + bb.y;
    r4.z = d * (acc.z + sv.z) + bb.z;
    r4.w = d * (acc.w + sv.w) + bb.w;
    if (RELU) {
        r4.x = fmaxf(r4.x, 0.f);
        r4.y = fmaxf(r4.y, 0.f);
        r4.z = fmaxf(r4.z, 0.f);
        r4.w = fmaxf(r4.w, 0.f);
    }
    ((float4*)(out + (long)node * F))[lane] = r4;
}

// ---------------- f32 GEMM v2: 128xNT tile, 8x8/8x4 microtile, row-scaled epilogue ----------------

template <int CG>
__global__ __launch_bounds__(256, 2) void gemm_f32_v2(const float* __restrict__ A,
                                                      const float* __restrict__ B,
                                                      float* __restrict__ C,
                                                      const float* __restrict__ rowscale,
                                                      int M, int K, int N) {
    constexpr int NT = CG * 64;
    __shared__ float As[16][132];       // transposed A tile [k][row]
    __shared__ float Bs[16][NT + 4];    // B tile [k][col]
    const int tid = threadIdx.x;
    const int tx = tid & 15;
    const int ty = tid >> 4;
    const int row0 = blockIdx.x * 128;
    const int col0 = blockIdx.y * NT;

    float acc[2][CG][4][4] = {};

    const int arow = tid >> 1;          // 0..127
    const int akc  = (tid & 1) * 8;     // 0 or 8
    const int bk   = tid >> 4;          // 0..15
    const int bn   = tx * (CG == 2 ? 8 : 4);

    const int agr = row0 + arow;
    const float* aptr = A + (long)agr * K + akc;
    const float* bptr = B + (long)bk * N + col0 + bn;

    for (int k0 = 0; k0 < K; k0 += 16) {
        float4 a0 = make_float4(0.f, 0.f, 0.f, 0.f), a1 = a0;
        if (agr < M) {
            a0 = *(const float4*)(aptr + k0);
            a1 = *(const float4*)(aptr + k0 + 4);
        }
        As[akc + 0][arow] = a0.x;
        As[akc + 1][arow] = a0.y;
        As[akc + 2][arow] = a0.z;
        As[akc + 3][arow] = a0.w;
        As[akc + 4][arow] = a1.x;
        As[akc + 5][arow] = a1.y;
        As[akc + 6][arow] = a1.z;
        As[akc + 7][arow] = a1.w;
        {
            const float* bp = bptr + (long)k0 * N;
            if (CG == 2) {
                *(float4*)&Bs[bk][bn]     = *(const float4*)bp;
                *(float4*)&Bs[bk][bn + 4] = *(const float4*)(bp + 4);
            } else {
                *(float4*)&Bs[bk][bn] = *(const float4*)bp;
            }
        }
        __syncthreads();

        #pragma unroll
        for (int k = 0; k < 16; k++) {
            float av[2][4], bv[CG][4];
            *(float4*)av[0] = *(const float4*)&As[k][ty * 4];
            *(float4*)av[1] = *(const float4*)&As[k][64 + ty * 4];
            #pragma unroll
            for (int g = 0; g < CG; g++)
                *(float4*)bv[g] = *(const float4*)&Bs[k][g * 64 + tx * 4];
            #pragma unroll
            for (int rg = 0; rg < 2; rg++)
                #pragma unroll
                for (int g = 0; g < CG; g++)
                    #pragma unroll
                    for (int i = 0; i < 4; i++)
                        #pragma unroll
                        for (int j = 0; j < 4; j++)
                            acc[rg][g][i][j] += av[rg][i] * bv[g][j];
        }
        __syncthreads();
    }

    #pragma unroll
    for (int rg = 0; rg < 2; rg++) {
        #pragma unroll
        for (int i = 0; i < 4; i++) {
            int gr = row0 + rg * 64 + ty * 4 + i;
            if (gr < M) {
                float sc = rowscale[gr];
                #pragma unroll
                for (int g = 0; g < CG; g++) {
                    float4 v = make_float4(acc[rg][g][i][0] * sc, acc[rg][g][i][1] * sc,
                                           acc[rg][g][i][2] * sc, acc[rg][g][i][3] * sc);
                    *(float4*)&C[(long)gr * N + col0 + g * 64 + tx * 4] = v;
                }
            }
        }
    }
}

// ---------------- pooling over sorted batch ----------------

__global__ void pool_kernel(const float* __restrict__ h,
                            const int* __restrict__ batch,
                            float* __restrict__ pooled,
                            int n) {
    int f = threadIdx.x;  // 0..63
    long start = (long)blockIdx.x * POOL_CHUNK;
    long end = start + POOL_CHUNK;
    if (end > n) end = n;
    if (start >= end) return;
    int cur = batch[start];
    float acc = 0.f;
    for (long i = start; i < end; i++) {
        int g = batch[i];
        if (g != cur) {
            atomicAdd(&pooled[cur * NCLASS + f], acc);
            acc = 0.f;
            cur = g;
        }
        acc += h[i * NCLASS + f];
    }
    atomicAdd(&pooled[cur * NCLASS + f], acc);
}

// ---------------- head: MLP + log_softmax + argmax ----------------

__global__ void head_kernel(const float* __restrict__ pooled,
                            const float* __restrict__ l1w,
                            const float* __restrict__ l1b,
                            const float* __restrict__ l2w,
                            const float* __restrict__ l2b,
                            float* __restrict__ out) {
    __shared__ float P[NCLASS * NUM_GRAPHS];  // transposed: P[c*64+g]
    for (int i = threadIdx.x; i < NUM_GRAPHS * NCLASS; i += 64) {
        int g = i >> 6, c = i & 63;
        P[c * 64 + g] = pooled[i];
    }
    __syncthreads();
    int g = threadIdx.x;
    float h[64];
    #pragma unroll 4
    for (int j = 0; j < 64; j++) {
        float a = l1b[j];
        for (int c = 0; c < 64; c++) a += P[c * 64 + g] * l1w[c * 64 + j];
        h[j] = fmaxf(a, 0.f);
    }
    float o0 = l2b[0], o1 = l2b[1];
    for (int j = 0; j < 64; j++) {
        o0 += h[j] * l2w[j * 2];
        o1 += h[j] * l2w[j * 2 + 1];
    }
    float m = fmaxf(o0, o1);
    float lse = m + logf(expf(o0 - m) + expf(o1 - m));
    out[g * 2 + 0] = o0 - lse;
    out[g * 2 + 1] = o1 - lse;
    out[128 + g] = (o1 > o0) ? 1.f : 0.f;
    out[192 + g * 2 + 0] = o0;
    out[192 + g * 2 + 1] = o1;
}

// ---------------- launch ----------------

extern "C" void kernel_launch(void* const* d_in, const int* in_sizes, int n_in,
                              void* d_out, int out_size, void* d_ws, size_t ws_size,
                              hipStream_t stream) {
    const float* x   = (const float*)d_in[0];           // [N, 256]
    const int* eidx  = (const int*)d_in[1];             // [2, E] flat
    const float* ew  = (const float*)d_in[2];           // [E]
    const int* batch = (const int*)d_in[3];             // [N]
    const float* W1  = (const float*)d_in[4];           // [256,128]
    const float* b1  = (const float*)d_in[5];
    const float* W2  = (const float*)d_in[6];           // [128,64]
    const float* b2  = (const float*)d_in[7];
    const float* l1w = (const float*)d_in[8];           // [64,64]
    const float* l1b = (const float*)d_in[9];
    const float* l2w = (const float*)d_in[10];          // [64,2]
    const float* l2b = (const float*)d_in[11];
    float* out = (float*)d_out;

    const int N = N_NODES, E = N_EDGES;
    const int* rows = eidx;
    const int* cols = eidx + E;

    // workspace layout (floats; 8B-aligned items first)
    float* ws = (float*)d_ws;
    unsigned long long* packed = (unsigned long long*)ws;  // N u64 = 2N floats
    float* dinv   = ws + 2 * N;              // N
    int*   cnt    = (int*)(dinv + N);        // N
    int*   starts = cnt + N;                 // N
    int*   cursor = starts + N;              // N
    int*   bsums  = cursor + N;              // 256
    int*   boff   = bsums + 256;             // 256
    int2*  edges  = (int2*)(boff + 256);     // E int2 = 2E floats (offset 600512: even)
    float* bufA   = (float*)(edges + E);     // N*128
    float* bufB   = bufA + (long)N * NHID1;  // N*128
    float* pooled = bufB + (long)N * NHID1;  // 4096
    float* hw2s = bufA;                      // [N,64] reuse
    float* h2   = bufA + (long)N * NCLASS;   // [N,64] reuse

    // 1. packed count+deg (1 atomic/edge), decode
    hipMemsetAsync(packed, 0, N * sizeof(unsigned long long), stream);
    count_deg_kernel<<<(E + 255) / 256, 256, 0, stream>>>(cols, ew, packed, E);
    decode_kernel<<<(N + 255) / 256, 256, 0, stream>>>(packed, cnt, dinv, N);

    // 2. prefix scan of cnt -> starts, cursor
    scan_reduce_kernel<<<SCAN_NB, 256, 0, stream>>>(cnt, bsums, N);
    scan_top_kernel<<<1, 64, 0, stream>>>(bsums, boff, SCAN_NB);
    scan_final_kernel<<<SCAN_NB, 256, 0, stream>>>(cnt, boff, starts, cursor, N);

    // 3. fill CSC edges (r, w) — 1 atomic + one 8B store per edge
    fill_kernel<<<(E + 255) / 256, 256, 0, stream>>>(rows, cols, ew, cursor, edges, E);

    // 4. GEMM1: bufA = (x @ W1) * dinv[row]
    {
        dim3 grid((N + 127) / 128, NHID1 / 128);
        gemm_f32_v2<2><<<grid, 256, 0, stream>>>(x, W1, bufA, dinv, N, NFEAT, NHID1);
    }

    // 5. gather layer 1: bufB = relu(dinv[c]*(agg + self) + b1)
    {
        long threads = (long)N * (NHID1 / 4);
        gather_agg_kernel<NHID1, true><<<(threads + 255) / 256, 256, 0, stream>>>(
            bufA, edges, starts, cnt, dinv, b1, bufB, N);
    }

    // 6. GEMM2: hw2s = (h1 @ W2) * dinv[row]
    {
        dim3 grid((N + 127) / 128, NCLASS / 64);
        gemm_f32_v2<1><<<grid, 256, 0, stream>>>(bufB, W2, hw2s, dinv, N, NHID1, NCLASS);
    }

    // 7. gather layer 2: h2 = relu(dinv[c]*(agg + self) + b2)
    {
        long threads = (long)N * (NCLASS / 4);
        gather_agg_kernel<NCLASS, true><<<(threads + 255) / 256, 256, 0, stream>>>(
            hw2s, edges, starts, cnt, dinv, b2, h2, N);
    }

    // 8. pool
    hipMemsetAsync(pooled, 0, NUM_GRAPHS * NCLASS * sizeof(float), stream);
    {
        int blocks = (N + POOL_CHUNK - 1) / POOL_CHUNK;
        pool_kernel<<<blocks, 64, 0, stream>>>(h2, batch, pooled, N);
    }

    // 9. head
    head_kernel<<<1, 64, 0, stream>>>(pooled, l1w, l1b, l2w, l2b, out);
}

// Round 6
// 689.845 us; speedup vs baseline: 7.0951x; 1.1783x over previous
//
#include <hip/hip_runtime.h>
#include <hip/hip_bf16.h>
#include <math.h>

#define N_NODES 100000
#define N_EDGES 1600000
#define NFEAT 256
#define NHID1 128
#define NCLASS 64
#define NUM_GRAPHS 64

// scan geometry: 98 blocks x 1024 elems
#define SCAN_CHUNK 1024
#define SCAN_NB ((N_NODES + SCAN_CHUNK - 1) / SCAN_CHUNK)

// pool geometry
#define POOL_CHUNK 64

// ---------------- pass 1: packed count+degree (ONE u64 atomic per edge) ----------------
// packed[c] bits 52..63 = in-edge count, bits 0..51 = sum(w) in 2^-32 fixed point.

__global__ void count_deg_kernel(const int* __restrict__ cols,
                                 const float* __restrict__ w,
                                 unsigned long long* __restrict__ packed, int nE) {
    int e = blockIdx.x * blockDim.x + threadIdx.x;
    if (e < nE) {
        int c = cols[e];
        unsigned long long fix = (unsigned long long)((double)w[e] * 4294967296.0 + 0.5);
        atomicAdd(&packed[c], (1ULL << 52) | fix);
    }
}

// decode: cnt + dinv (deg = 1 + sum(w), self-loop included)
__global__ void decode_kernel(const unsigned long long* __restrict__ packed,
                              int* __restrict__ cnt,
                              float* __restrict__ dinv, int n) {
    int i = blockIdx.x * blockDim.x + threadIdx.x;
    if (i < n) {
        unsigned long long p = packed[i];
        cnt[i] = (int)(p >> 52);
        double degw = (double)(p & ((1ULL << 52) - 1)) * (1.0 / 4294967296.0);
        float deg = (float)(1.0 + degw);
        dinv[i] = rsqrtf(deg);
    }
}

// ---------------- prefix scan (3 kernels) ----------------

__global__ __launch_bounds__(256) void scan_reduce_kernel(const int* __restrict__ cnt,
                                                          int* __restrict__ bsums, int n) {
    __shared__ int sdata[256];
    int b = blockIdx.x, t = threadIdx.x;
    int base = b * SCAN_CHUNK + t * 4;
    int s = 0;
    #pragma unroll
    for (int i = 0; i < 4; i++) {
        int idx = base + i;
        if (idx < n) s += cnt[idx];
    }
    sdata[t] = s;
    __syncthreads();
    for (int off = 128; off > 0; off >>= 1) {
        if (t < off) sdata[t] += sdata[t + off];
        __syncthreads();
    }
    if (t == 0) bsums[b] = sdata[0];
}

__global__ void scan_top_kernel(const int* __restrict__ bsums, int* __restrict__ boff, int nb) {
    if (threadIdx.x == 0 && blockIdx.x == 0) {
        int acc = 0;
        for (int i = 0; i < nb; i++) {
            boff[i] = acc;
            acc += bsums[i];
        }
    }
}

__global__ __launch_bounds__(256) void scan_final_kernel(const int* __restrict__ cnt,
                                                         const int* __restrict__ boff,
                                                         int* __restrict__ starts,
                                                         int* __restrict__ cursor, int n) {
    __shared__ int sdata[256];
    int b = blockIdx.x, t = threadIdx.x;
    int base = b * SCAN_CHUNK + t * 4;
    int v[4];
    int s = 0;
    #pragma unroll
    for (int i = 0; i < 4; i++) {
        int idx = base + i;
        v[i] = (idx < n) ? cnt[idx] : 0;
        s += v[i];
    }
    sdata[t] = s;
    __syncthreads();
    for (int off = 1; off < 256; off <<= 1) {
        int add = (t >= off) ? sdata[t - off] : 0;
        __syncthreads();
        sdata[t] += add;
        __syncthreads();
    }
    int run = sdata[t] - s + boff[b];
    #pragma unroll
    for (int i = 0; i < 4; i++) {
        int idx = base + i;
        if (idx < n) {
            starts[idx] = run;
            cursor[idx] = run;
        }
        run += v[i];
    }
}

// ---------------- fill CSC: one 8B store per edge ----------------

__global__ void fill_kernel(const int* __restrict__ rows,
                            const int* __restrict__ cols,
                            const float* __restrict__ w,
                            int* __restrict__ cursor,
                            int2* __restrict__ edges, int nE) {
    int e = blockIdx.x * blockDim.x + threadIdx.x;
    if (e < nE) {
        int c = cols[e], r = rows[e];
        int pos = atomicAdd(&cursor[c], 1);
        edges[pos] = make_int2(r, __float_as_int(w[e]));
    }
}

// ---------------- gather-aggregate (dinv pre-folded into features) ----------------
// xs[i] = (x@W)[i] * dinv[i].  out[c] = relu(dinv[c]*(sum_e w_e*xs[r_e] + xs[c]) + b)

template <int F, bool RELU>
__global__ __launch_bounds__(256) void gather_agg_kernel(const float* __restrict__ xs,
                                                         const int2* __restrict__ edges,
                                                         const int* __restrict__ starts,
                                                         const int* __restrict__ cnt,
                                                         const float* __restrict__ dinv,
                                                         const float* __restrict__ bias,
                                                         float* __restrict__ out, int n) {
    constexpr int G = F / 4;  // lanes per node
    int gt = blockIdx.x * blockDim.x + threadIdx.x;
    int node = gt / G;
    int lane = gt - node * G;
    if (node >= n) return;

    int s = starts[node];
    int c = cnt[node];
    float4 acc = make_float4(0.f, 0.f, 0.f, 0.f);
    for (int j = s; j < s + c; j++) {
        int2 ed = edges[j];
        float wv = __int_as_float(ed.y);
        float4 v = ((const float4*)(xs + (long)ed.x * F))[lane];
        acc.x += v.x * wv;
        acc.y += v.y * wv;
        acc.z += v.z * wv;
        acc.w += v.w * wv;
    }
    float d = dinv[node];
    float4 sv = ((const float4*)(xs + (long)node * F))[lane];
    float4 bb = ((const float4*)bias)[lane];
    float4 r4;
    r4.x = d * (acc.x + sv.x) + bb.x;
    r4.y = d * (acc.y + sv.y) + bb.y;
    r4.z = d * (acc.z + sv.z) + bb.z;
    r4.w = d * (acc.w + sv.w) + bb.w;
    if (RELU) {
        r4.x = fmaxf(r4.x, 0.f);
        r4.y = fmaxf(r4.y, 0.f);
        r4.z = fmaxf(r4.z, 0.f);
        r4.w = fmaxf(r4.w, 0.f);
    }
    ((float4*)(out + (long)node * F))[lane] = r4;
}

// ---------------- f32 GEMM v2: 128xNT tile, 8x8/8x4 microtile, row-scaled epilogue ----------------

template <int CG>
__global__ __launch_bounds__(256, 2) void gemm_f32_v2(const float* __restrict__ A,
                                                      const float* __restrict__ B,
                                                      float* __restrict__ C,
                                                      const float* __restrict__ rowscale,
                                                      int M, int K, int N) {
    constexpr int NT = CG * 64;
    __shared__ float As[16][132];       // transposed A tile [k][row]
    __shared__ float Bs[16][NT + 4];    // B tile [k][col]
    const int tid = threadIdx.x;
    const int tx = tid & 15;
    const int ty = tid >> 4;
    const int row0 = blockIdx.x * 128;
    const int col0 = blockIdx.y * NT;

    float acc[2][CG][4][4] = {};

    const int arow = tid >> 1;          // 0..127
    const int akc  = (tid & 1) * 8;     // 0 or 8
    const int bk   = tid >> 4;          // 0..15
    const int bn   = tx * (CG == 2 ? 8 : 4);

    const int agr = row0 + arow;
    const float* aptr = A + (long)agr * K + akc;
    const float* bptr = B + (long)bk * N + col0 + bn;

    for (int k0 = 0; k0 < K; k0 += 16) {
        float4 a0 = make_float4(0.f, 0.f, 0.f, 0.f), a1 = a0;
        if (agr < M) {
            a0 = *(const float4*)(aptr + k0);
            a1 = *(const float4*)(aptr + k0 + 4);
        }
        As[akc + 0][arow] = a0.x;
        As[akc + 1][arow] = a0.y;
        As[akc + 2][arow] = a0.z;
        As[akc + 3][arow] = a0.w;
        As[akc + 4][arow] = a1.x;
        As[akc + 5][arow] = a1.y;
        As[akc + 6][arow] = a1.z;
        As[akc + 7][arow] = a1.w;
        {
            const float* bp = bptr + (long)k0 * N;
            if (CG == 2) {
                *(float4*)&Bs[bk][bn]     = *(const float4*)bp;
                *(float4*)&Bs[bk][bn + 4] = *(const float4*)(bp + 4);
            } else {
                *(float4*)&Bs[bk][bn] = *(const float4*)bp;
            }
        }
        __syncthreads();

        #pragma unroll
        for (int k = 0; k < 16; k++) {
            float av[2][4], bv[CG][4];
            *(float4*)av[0] = *(const float4*)&As[k][ty * 4];
            *(float4*)av[1] = *(const float4*)&As[k][64 + ty * 4];
            #pragma unroll
            for (int g = 0; g < CG; g++)
                *(float4*)bv[g] = *(const float4*)&Bs[k][g * 64 + tx * 4];
            #pragma unroll
            for (int rg = 0; rg < 2; rg++)
                #pragma unroll
                for (int g = 0; g < CG; g++)
                    #pragma unroll
                    for (int i = 0; i < 4; i++)
                        #pragma unroll
                        for (int j = 0; j < 4; j++)
                            acc[rg][g][i][j] += av[rg][i] * bv[g][j];
        }
        __syncthreads();
    }

    #pragma unroll
    for (int rg = 0; rg < 2; rg++) {
        #pragma unroll
        for (int i = 0; i < 4; i++) {
            int gr = row0 + rg * 64 + ty * 4 + i;
            if (gr < M) {
                float sc = rowscale[gr];
                #pragma unroll
                for (int g = 0; g < CG; g++) {
                    float4 v = make_float4(acc[rg][g][i][0] * sc, acc[rg][g][i][1] * sc,
                                           acc[rg][g][i][2] * sc, acc[rg][g][i][3] * sc);
                    *(float4*)&C[(long)gr * N + col0 + g * 64 + tx * 4] = v;
                }
            }
        }
    }
}

// ---------------- pooling over sorted batch ----------------

__global__ void pool_kernel(const float* __restrict__ h,
                            const int* __restrict__ batch,
                            float* __restrict__ pooled,
                            int n) {
    int f = threadIdx.x;  // 0..63
    long start = (long)blockIdx.x * POOL_CHUNK;
    long end = start + POOL_CHUNK;
    if (end > n) end = n;
    if (start >= end) return;
    int cur = batch[start];
    float acc = 0.f;
    for (long i = start; i < end; i++) {
        int g = batch[i];
        if (g != cur) {
            atomicAdd(&pooled[cur * NCLASS + f], acc);
            acc = 0.f;
            cur = g;
        }
        acc += h[i * NCLASS + f];
    }
    atomicAdd(&pooled[cur * NCLASS + f], acc);
}

// ---------------- head v2: 256 threads, all-LDS MLP + log_softmax + argmax ----------------
// thread = (g, q): graph g, feature quad q (16 of the 64 hidden units).
// P, W staged in padded LDS; h kept in registers; o0/o1 reduced via LDS.

__global__ __launch_bounds__(256) void head_kernel(const float* __restrict__ pooled,
                                                   const float* __restrict__ l1w,
                                                   const float* __restrict__ l1b,
                                                   const float* __restrict__ l2w,
                                                   const float* __restrict__ l2b,
                                                   float* __restrict__ out) {
    __shared__ float P[64][68];   // P[g][c], pad 68 keeps float4 align, breaks g-stride banks
    __shared__ float W[64][68];   // W[c][j]
    __shared__ float red0[64][4];
    __shared__ float red1[64][4];
    const int tid = threadIdx.x;

    // stage pooled [64x64] and l1w [64x64]: 1024 float4 each, 4 per thread
    for (int i = tid; i < 1024; i += 256) {
        int r = i >> 4;
        int cq = (i & 15) * 4;
        *(float4*)&P[r][cq] = *(const float4*)&pooled[r * 64 + cq];
        *(float4*)&W[r][cq] = *(const float4*)&l1w[r * 64 + cq];
    }
    __syncthreads();

    const int g = tid >> 2;       // 0..63
    const int q = tid & 3;        // 0..3
    const int j0 = q * 16;

    float hacc[16];
    #pragma unroll
    for (int jj = 0; jj < 16; jj++) hacc[jj] = l1b[j0 + jj];

    for (int c = 0; c < 64; c++) {
        float pv = P[g][c];
        #pragma unroll
        for (int jj = 0; jj < 16; jj += 4) {
            float4 wv = *(const float4*)&W[c][j0 + jj];
            hacc[jj + 0] += pv * wv.x;
            hacc[jj + 1] += pv * wv.y;
            hacc[jj + 2] += pv * wv.z;
            hacc[jj + 3] += pv * wv.w;
        }
    }

    float o0 = 0.f, o1 = 0.f;
    #pragma unroll
    for (int jj = 0; jj < 16; jj++) {
        float h = fmaxf(hacc[jj], 0.f);
        o0 += h * l2w[(j0 + jj) * 2];
        o1 += h * l2w[(j0 + jj) * 2 + 1];
    }
    red0[g][q] = o0;
    red1[g][q] = o1;
    __syncthreads();

    if (q == 0) {
        float a0 = red0[g][0] + red0[g][1] + red0[g][2] + red0[g][3] + l2b[0];
        float a1 = red1[g][0] + red1[g][1] + red1[g][2] + red1[g][3] + l2b[1];
        float m = fmaxf(a0, a1);
        float lse = m + logf(expf(a0 - m) + expf(a1 - m));
        out[g * 2 + 0] = a0 - lse;
        out[g * 2 + 1] = a1 - lse;
        out[128 + g] = (a1 > a0) ? 1.f : 0.f;
        out[192 + g * 2 + 0] = a0;
        out[192 + g * 2 + 1] = a1;
    }
}

// ---------------- launch ----------------

extern "C" void kernel_launch(void* const* d_in, const int* in_sizes, int n_in,
                              void* d_out, int out_size, void* d_ws, size_t ws_size,
                              hipStream_t stream) {
    const float* x   = (const float*)d_in[0];           // [N, 256]
    const int* eidx  = (const int*)d_in[1];             // [2, E] flat
    const float* ew  = (const float*)d_in[2];           // [E]
    const int* batch = (const int*)d_in[3];             // [N]
    const float* W1  = (const float*)d_in[4];           // [256,128]
    const float* b1  = (const float*)d_in[5];
    const float* W2  = (const float*)d_in[6];           // [128,64]
    const float* b2  = (const float*)d_in[7];
    const float* l1w = (const float*)d_in[8];           // [64,64]
    const float* l1b = (const float*)d_in[9];
    const float* l2w = (const float*)d_in[10];          // [64,2]
    const float* l2b = (const float*)d_in[11];
    float* out = (float*)d_out;

    const int N = N_NODES, E = N_EDGES;
    const int* rows = eidx;
    const int* cols = eidx + E;

    // workspace layout (floats; 8B-aligned items first)
    float* ws = (float*)d_ws;
    unsigned long long* packed = (unsigned long long*)ws;  // N u64 = 2N floats
    float* dinv   = ws + 2 * N;              // N
    int*   cnt    = (int*)(dinv + N);        // N
    int*   starts = cnt + N;                 // N
    int*   cursor = starts + N;              // N
    int*   bsums  = cursor + N;              // 256
    int*   boff   = bsums + 256;             // 256
    int2*  edges  = (int2*)(boff + 256);     // E int2 = 2E floats
    float* bufA   = (float*)(edges + E);     // N*128
    float* bufB   = bufA + (long)N * NHID1;  // N*128
    float* pooled = bufB + (long)N * NHID1;  // 4096
    float* hw2s = bufA;                      // [N,64] reuse
    float* h2   = bufA + (long)N * NCLASS;   // [N,64] reuse

    // 1. packed count+deg (1 atomic/edge), decode
    hipMemsetAsync(packed, 0, N * sizeof(unsigned long long), stream);
    count_deg_kernel<<<(E + 255) / 256, 256, 0, stream>>>(cols, ew, packed, E);
    decode_kernel<<<(N + 255) / 256, 256, 0, stream>>>(packed, cnt, dinv, N);

    // 2. prefix scan of cnt -> starts, cursor
    scan_reduce_kernel<<<SCAN_NB, 256, 0, stream>>>(cnt, bsums, N);
    scan_top_kernel<<<1, 64, 0, stream>>>(bsums, boff, SCAN_NB);
    scan_final_kernel<<<SCAN_NB, 256, 0, stream>>>(cnt, boff, starts, cursor, N);

    // 3. fill CSC edges (r, w) — 1 atomic + one 8B store per edge
    fill_kernel<<<(E + 255) / 256, 256, 0, stream>>>(rows, cols, ew, cursor, edges, E);

    // 4. GEMM1: bufA = (x @ W1) * dinv[row]
    {
        dim3 grid((N + 127) / 128, NHID1 / 128);
        gemm_f32_v2<2><<<grid, 256, 0, stream>>>(x, W1, bufA, dinv, N, NFEAT, NHID1);
    }

    // 5. gather layer 1: bufB = relu(dinv[c]*(agg + self) + b1)
    {
        long threads = (long)N * (NHID1 / 4);
        gather_agg_kernel<NHID1, true><<<(threads + 255) / 256, 256, 0, stream>>>(
            bufA, edges, starts, cnt, dinv, b1, bufB, N);
    }

    // 6. GEMM2: hw2s = (h1 @ W2) * dinv[row]
    {
        dim3 grid((N + 127) / 128, NCLASS / 64);
        gemm_f32_v2<1><<<grid, 256, 0, stream>>>(bufB, W2, hw2s, dinv, N, NHID1, NCLASS);
    }

    // 7. gather layer 2: h2 = relu(dinv[c]*(agg + self) + b2)
    {
        long threads = (long)N * (NCLASS / 4);
        gather_agg_kernel<NCLASS, true><<<(threads + 255) / 256, 256, 0, stream>>>(
            hw2s, edges, starts, cnt, dinv, b2, h2, N);
    }

    // 8. pool
    hipMemsetAsync(pooled, 0, NUM_GRAPHS * NCLASS * sizeof(float), stream);
    {
        int blocks = (N + POOL_CHUNK - 1) / POOL_CHUNK;
        pool_kernel<<<blocks, 64, 0, stream>>>(h2, batch, pooled, N);
    }

    // 9. head
    head_kernel<<<1, 256, 0, stream>>>(pooled, l1w, l1b, l2w, l2b, out);
}

// Round 7
// 637.784 us; speedup vs baseline: 7.6743x; 1.0816x over previous
//
#include <hip/hip_runtime.h>
#include <hip/hip_bf16.h>
#include <math.h>

#define N_NODES 100000
#define N_EDGES 1600000
#define NFEAT 256
#define NHID1 128
#define NCLASS 64
#define NUM_GRAPHS 64

// scan geometry: 98 blocks x 1024 elems
#define SCAN_CHUNK 1024
#define SCAN_NB ((N_NODES + SCAN_CHUNK - 1) / SCAN_CHUNK)

// pool geometry
#define POOL_CHUNK 64

// ---------------- bf16 helpers (bit-level, RNE) ----------------

__device__ __forceinline__ unsigned short f2bf(float f) {
    unsigned u = __float_as_uint(f);
    u += 0x7fffu + ((u >> 16) & 1u);   // round to nearest even
    return (unsigned short)(u >> 16);
}
__device__ __forceinline__ unsigned packbf2(float lo, float hi) {
    return (unsigned)f2bf(lo) | ((unsigned)f2bf(hi) << 16);
}
__device__ __forceinline__ float bflo(unsigned p) { return __uint_as_float(p << 16); }
__device__ __forceinline__ float bfhi(unsigned p) { return __uint_as_float(p & 0xffff0000u); }

// ---------------- pass 1: packed count+degree (ONE u64 atomic per edge) ----------------
// packed[c] bits 52..63 = in-edge count, bits 0..51 = sum(w) in 2^-32 fixed point.

__global__ void count_deg_kernel(const int* __restrict__ cols,
                                 const float* __restrict__ w,
                                 unsigned long long* __restrict__ packed, int nE) {
    int e = blockIdx.x * blockDim.x + threadIdx.x;
    if (e < nE) {
        int c = cols[e];
        unsigned long long fix = (unsigned long long)((double)w[e] * 4294967296.0 + 0.5);
        atomicAdd(&packed[c], (1ULL << 52) | fix);
    }
}

__global__ void decode_kernel(const unsigned long long* __restrict__ packed,
                              int* __restrict__ cnt,
                              float* __restrict__ dinv, int n) {
    int i = blockIdx.x * blockDim.x + threadIdx.x;
    if (i < n) {
        unsigned long long p = packed[i];
        cnt[i] = (int)(p >> 52);
        double degw = (double)(p & ((1ULL << 52) - 1)) * (1.0 / 4294967296.0);
        float deg = (float)(1.0 + degw);
        dinv[i] = rsqrtf(deg);
    }
}

// ---------------- prefix scan (3 kernels) ----------------

__global__ __launch_bounds__(256) void scan_reduce_kernel(const int* __restrict__ cnt,
                                                          int* __restrict__ bsums, int n) {
    __shared__ int sdata[256];
    int b = blockIdx.x, t = threadIdx.x;
    int base = b * SCAN_CHUNK + t * 4;
    int s = 0;
    #pragma unroll
    for (int i = 0; i < 4; i++) {
        int idx = base + i;
        if (idx < n) s += cnt[idx];
    }
    sdata[t] = s;
    __syncthreads();
    for (int off = 128; off > 0; off >>= 1) {
        if (t < off) sdata[t] += sdata[t + off];
        __syncthreads();
    }
    if (t == 0) bsums[b] = sdata[0];
}

__global__ void scan_top_kernel(const int* __restrict__ bsums, int* __restrict__ boff, int nb) {
    if (threadIdx.x == 0 && blockIdx.x == 0) {
        int acc = 0;
        for (int i = 0; i < nb; i++) {
            boff[i] = acc;
            acc += bsums[i];
        }
    }
}

__global__ __launch_bounds__(256) void scan_final_kernel(const int* __restrict__ cnt,
                                                         const int* __restrict__ boff,
                                                         int* __restrict__ starts,
                                                         int* __restrict__ cursor, int n) {
    __shared__ int sdata[256];
    int b = blockIdx.x, t = threadIdx.x;
    int base = b * SCAN_CHUNK + t * 4;
    int v[4];
    int s = 0;
    #pragma unroll
    for (int i = 0; i < 4; i++) {
        int idx = base + i;
        v[i] = (idx < n) ? cnt[idx] : 0;
        s += v[i];
    }
    sdata[t] = s;
    __syncthreads();
    for (int off = 1; off < 256; off <<= 1) {
        int add = (t >= off) ? sdata[t - off] : 0;
        __syncthreads();
        sdata[t] += add;
        __syncthreads();
    }
    int run = sdata[t] - s + boff[b];
    #pragma unroll
    for (int i = 0; i < 4; i++) {
        int idx = base + i;
        if (idx < n) {
            starts[idx] = run;
            cursor[idx] = run;
        }
        run += v[i];
    }
}

// ---------------- fill CSC: one 8B store per edge ----------------

__global__ void fill_kernel(const int* __restrict__ rows,
                            const int* __restrict__ cols,
                            const float* __restrict__ w,
                            int* __restrict__ cursor,
                            int2* __restrict__ edges, int nE) {
    int e = blockIdx.x * blockDim.x + threadIdx.x;
    if (e < nE) {
        int c = cols[e], r = rows[e];
        int pos = atomicAdd(&cursor[c], 1);
        edges[pos] = make_int2(r, __float_as_int(w[e]));
    }
}

// ---------------- gather-aggregate over bf16 features ----------------
// xsb: bf16[n][F] viewed as unsigned pairs. out[c] = relu(dinv[c]*(sum_e w_e*xs[r_e] + xs[c]) + b), f32.

template <int F, bool RELU>
__global__ __launch_bounds__(256) void gather_agg_bf(const unsigned* __restrict__ xsb,
                                                     const int2* __restrict__ edges,
                                                     const int* __restrict__ starts,
                                                     const int* __restrict__ cnt,
                                                     const float* __restrict__ dinv,
                                                     const float* __restrict__ bias,
                                                     float* __restrict__ out, int n) {
    constexpr int G = F / 8;        // lanes per node; each lane covers 8 features (16 B)
    constexpr int FU = F / 2;       // uints per row
    int gt = blockIdx.x * blockDim.x + threadIdx.x;
    int node = gt / G;
    int lane = gt - node * G;
    if (node >= n) return;

    int s = starts[node];
    int c = cnt[node];
    float acc[8] = {};
    const unsigned* lbase = xsb + lane * 4;
    for (int j = s; j < s + c; j++) {
        int2 ed = edges[j];
        float wv = __int_as_float(ed.y);
        uint4 p = *(const uint4*)(lbase + (long)ed.x * FU);
        acc[0] += bflo(p.x) * wv; acc[1] += bfhi(p.x) * wv;
        acc[2] += bflo(p.y) * wv; acc[3] += bfhi(p.y) * wv;
        acc[4] += bflo(p.z) * wv; acc[5] += bfhi(p.z) * wv;
        acc[6] += bflo(p.w) * wv; acc[7] += bfhi(p.w) * wv;
    }
    float d = dinv[node];
    uint4 sp = *(const uint4*)(lbase + (long)node * FU);
    float sv[8] = { bflo(sp.x), bfhi(sp.x), bflo(sp.y), bfhi(sp.y),
                    bflo(sp.z), bfhi(sp.z), bflo(sp.w), bfhi(sp.w) };
    float4 bb0 = ((const float4*)bias)[lane * 2];
    float4 bb1 = ((const float4*)bias)[lane * 2 + 1];
    float bbv[8] = { bb0.x, bb0.y, bb0.z, bb0.w, bb1.x, bb1.y, bb1.z, bb1.w };
    float r[8];
    #pragma unroll
    for (int i = 0; i < 8; i++) {
        float v = d * (acc[i] + sv[i]) + bbv[i];
        r[i] = RELU ? fmaxf(v, 0.f) : v;
    }
    float* o = out + (long)node * F + lane * 8;
    *(float4*)o       = make_float4(r[0], r[1], r[2], r[3]);
    *(float4*)(o + 4) = make_float4(r[4], r[5], r[6], r[7]);
}

// ---------------- f32 GEMM: 128xNT tile, row-scaled epilogue, optional bf16 output ----------------

template <int CG, bool BF16OUT>
__global__ __launch_bounds__(256, 2) void gemm_f32_v2(const float* __restrict__ A,
                                                      const float* __restrict__ B,
                                                      void* __restrict__ Cv,
                                                      const float* __restrict__ rowscale,
                                                      int M, int K, int N) {
    constexpr int NT = CG * 64;
    __shared__ float As[16][132];       // transposed A tile [k][row]
    __shared__ float Bs[16][NT + 4];    // B tile [k][col]
    const int tid = threadIdx.x;
    const int tx = tid & 15;
    const int ty = tid >> 4;
    const int row0 = blockIdx.x * 128;
    const int col0 = blockIdx.y * NT;

    float acc[2][CG][4][4] = {};

    const int arow = tid >> 1;          // 0..127
    const int akc  = (tid & 1) * 8;     // 0 or 8
    const int bk   = tid >> 4;          // 0..15
    const int bn   = tx * (CG == 2 ? 8 : 4);

    const int agr = row0 + arow;
    const float* aptr = A + (long)agr * K + akc;
    const float* bptr = B + (long)bk * N + col0 + bn;

    for (int k0 = 0; k0 < K; k0 += 16) {
        float4 a0 = make_float4(0.f, 0.f, 0.f, 0.f), a1 = a0;
        if (agr < M) {
            a0 = *(const float4*)(aptr + k0);
            a1 = *(const float4*)(aptr + k0 + 4);
        }
        As[akc + 0][arow] = a0.x;
        As[akc + 1][arow] = a0.y;
        As[akc + 2][arow] = a0.z;
        As[akc + 3][arow] = a0.w;
        As[akc + 4][arow] = a1.x;
        As[akc + 5][arow] = a1.y;
        As[akc + 6][arow] = a1.z;
        As[akc + 7][arow] = a1.w;
        {
            const float* bp = bptr + (long)k0 * N;
            if (CG == 2) {
                *(float4*)&Bs[bk][bn]     = *(const float4*)bp;
                *(float4*)&Bs[bk][bn + 4] = *(const float4*)(bp + 4);
            } else {
                *(float4*)&Bs[bk][bn] = *(const float4*)bp;
            }
        }
        __syncthreads();

        #pragma unroll
        for (int k = 0; k < 16; k++) {
            float av[2][4], bv[CG][4];
            *(float4*)av[0] = *(const float4*)&As[k][ty * 4];
            *(float4*)av[1] = *(const float4*)&As[k][64 + ty * 4];
            #pragma unroll
            for (int g = 0; g < CG; g++)
                *(float4*)bv[g] = *(const float4*)&Bs[k][g * 64 + tx * 4];
            #pragma unroll
            for (int rg = 0; rg < 2; rg++)
                #pragma unroll
                for (int g = 0; g < CG; g++)
                    #pragma unroll
                    for (int i = 0; i < 4; i++)
                        #pragma unroll
                        for (int j = 0; j < 4; j++)
                            acc[rg][g][i][j] += av[rg][i] * bv[g][j];
        }
        __syncthreads();
    }

    #pragma unroll
    for (int rg = 0; rg < 2; rg++) {
        #pragma unroll
        for (int i = 0; i < 4; i++) {
            int gr = row0 + rg * 64 + ty * 4 + i;
            if (gr < M) {
                float sc = rowscale[gr];
                #pragma unroll
                for (int g = 0; g < CG; g++) {
                    float v0 = acc[rg][g][i][0] * sc;
                    float v1 = acc[rg][g][i][1] * sc;
                    float v2 = acc[rg][g][i][2] * sc;
                    float v3 = acc[rg][g][i][3] * sc;
                    if (BF16OUT) {
                        unsigned* C = (unsigned*)Cv;
                        uint2 pk = make_uint2(packbf2(v0, v1), packbf2(v2, v3));
                        *(uint2*)(C + (long)gr * (N / 2) + (col0 + g * 64 + tx * 4) / 2) = pk;
                    } else {
                        float* C = (float*)Cv;
                        *(float4*)&C[(long)gr * N + col0 + g * 64 + tx * 4] =
                            make_float4(v0, v1, v2, v3);
                    }
                }
            }
        }
    }
}

// ---------------- pooling over sorted batch ----------------

__global__ void pool_kernel(const float* __restrict__ h,
                            const int* __restrict__ batch,
                            float* __restrict__ pooled,
                            int n) {
    int f = threadIdx.x;  // 0..63
    long start = (long)blockIdx.x * POOL_CHUNK;
    long end = start + POOL_CHUNK;
    if (end > n) end = n;
    if (start >= end) return;
    int cur = batch[start];
    float acc = 0.f;
    for (long i = start; i < end; i++) {
        int g = batch[i];
        if (g != cur) {
            atomicAdd(&pooled[cur * NCLASS + f], acc);
            acc = 0.f;
            cur = g;
        }
        acc += h[i * NCLASS + f];
    }
    atomicAdd(&pooled[cur * NCLASS + f], acc);
}

// ---------------- head: 256 threads, all-LDS MLP + log_softmax + argmax ----------------

__global__ __launch_bounds__(256) void head_kernel(const float* __restrict__ pooled,
                                                   const float* __restrict__ l1w,
                                                   const float* __restrict__ l1b,
                                                   const float* __restrict__ l2w,
                                                   const float* __restrict__ l2b,
                                                   float* __restrict__ out) {
    __shared__ float P[64][68];
    __shared__ float W[64][68];
    __shared__ float red0[64][4];
    __shared__ float red1[64][4];
    const int tid = threadIdx.x;

    for (int i = tid; i < 1024; i += 256) {
        int r = i >> 4;
        int cq = (i & 15) * 4;
        *(float4*)&P[r][cq] = *(const float4*)&pooled[r * 64 + cq];
        *(float4*)&W[r][cq] = *(const float4*)&l1w[r * 64 + cq];
    }
    __syncthreads();

    const int g = tid >> 2;
    const int q = tid & 3;
    const int j0 = q * 16;

    float hacc[16];
    #pragma unroll
    for (int jj = 0; jj < 16; jj++) hacc[jj] = l1b[j0 + jj];

    for (int c = 0; c < 64; c++) {
        float pv = P[g][c];
        #pragma unroll
        for (int jj = 0; jj < 16; jj += 4) {
            float4 wv = *(const float4*)&W[c][j0 + jj];
            hacc[jj + 0] += pv * wv.x;
            hacc[jj + 1] += pv * wv.y;
            hacc[jj + 2] += pv * wv.z;
            hacc[jj + 3] += pv * wv.w;
        }
    }

    float o0 = 0.f, o1 = 0.f;
    #pragma unroll
    for (int jj = 0; jj < 16; jj++) {
        float h = fmaxf(hacc[jj], 0.f);
        o0 += h * l2w[(j0 + jj) * 2];
        o1 += h * l2w[(j0 + jj) * 2 + 1];
    }
    red0[g][q] = o0;
    red1[g][q] = o1;
    __syncthreads();

    if (q == 0) {
        float a0 = red0[g][0] + red0[g][1] + red0[g][2] + red0[g][3] + l2b[0];
        float a1 = red1[g][0] + red1[g][1] + red1[g][2] + red1[g][3] + l2b[1];
        float m = fmaxf(a0, a1);
        float lse = m + logf(expf(a0 - m) + expf(a1 - m));
        out[g * 2 + 0] = a0 - lse;
        out[g * 2 + 1] = a1 - lse;
        out[128 + g] = (a1 > a0) ? 1.f : 0.f;
        out[192 + g * 2 + 0] = a0;
        out[192 + g * 2 + 1] = a1;
    }
}

// ---------------- launch ----------------

extern "C" void kernel_launch(void* const* d_in, const int* in_sizes, int n_in,
                              void* d_out, int out_size, void* d_ws, size_t ws_size,
                              hipStream_t stream) {
    const float* x   = (const float*)d_in[0];           // [N, 256]
    const int* eidx  = (const int*)d_in[1];             // [2, E] flat
    const float* ew  = (const float*)d_in[2];           // [E]
    const int* batch = (const int*)d_in[3];             // [N]
    const float* W1  = (const float*)d_in[4];           // [256,128]
    const float* b1  = (const float*)d_in[5];
    const float* W2  = (const float*)d_in[6];           // [128,64]
    const float* b2  = (const float*)d_in[7];
    const float* l1w = (const float*)d_in[8];           // [64,64]
    const float* l1b = (const float*)d_in[9];
    const float* l2w = (const float*)d_in[10];          // [64,2]
    const float* l2b = (const float*)d_in[11];
    float* out = (float*)d_out;

    const int N = N_NODES, E = N_EDGES;
    const int* rows = eidx;
    const int* cols = eidx + E;

    // workspace layout (floats; 8B-aligned items first)
    float* ws = (float*)d_ws;
    unsigned long long* packed = (unsigned long long*)ws;  // N u64 = 2N floats
    float* dinv   = ws + 2 * N;              // N
    int*   cnt    = (int*)(dinv + N);        // N
    int*   starts = cnt + N;                 // N
    int*   cursor = starts + N;              // N
    int*   bsums  = cursor + N;              // 256
    int*   boff   = bsums + 256;             // 256
    int2*  edges  = (int2*)(boff + 256);     // E int2 (16B-aligned: offset 600512 floats)
    unsigned* xsb = (unsigned*)(edges + E);  // N*64 uints = N*128 bf16 (25.6 MB)
    float* bufB   = (float*)(xsb + (long)N * 64);   // N*128 f32 (h1)
    float* pooled = bufB + (long)N * NHID1;  // 4096
    // reuse regions:
    unsigned* hw2b = xsb;                    // N*32 uints = N*64 bf16 (in dead xsb)
    float* h2 = bufB;                        // N*64 f32 (in dead bufB after GEMM2 reads it)

    // 1. packed count+deg (1 atomic/edge), decode
    hipMemsetAsync(packed, 0, N * sizeof(unsigned long long), stream);
    count_deg_kernel<<<(E + 255) / 256, 256, 0, stream>>>(cols, ew, packed, E);
    decode_kernel<<<(N + 255) / 256, 256, 0, stream>>>(packed, cnt, dinv, N);

    // 2. prefix scan of cnt -> starts, cursor
    scan_reduce_kernel<<<SCAN_NB, 256, 0, stream>>>(cnt, bsums, N);
    scan_top_kernel<<<1, 64, 0, stream>>>(bsums, boff, SCAN_NB);
    scan_final_kernel<<<SCAN_NB, 256, 0, stream>>>(cnt, boff, starts, cursor, N);

    // 3. fill CSC edges (r, w)
    fill_kernel<<<(E + 255) / 256, 256, 0, stream>>>(rows, cols, ew, cursor, edges, E);

    // 4. GEMM1: xsb = bf16((x @ W1) * dinv[row])
    {
        dim3 grid((N + 127) / 128, NHID1 / 128);
        gemm_f32_v2<2, true><<<grid, 256, 0, stream>>>(x, W1, xsb, dinv, N, NFEAT, NHID1);
    }

    // 5. gather layer 1: bufB = relu(dinv[c]*(agg + self) + b1), f32
    {
        long threads = (long)N * (NHID1 / 8);
        gather_agg_bf<NHID1, true><<<(threads + 255) / 256, 256, 0, stream>>>(
            xsb, edges, starts, cnt, dinv, b1, bufB, N);
    }

    // 6. GEMM2: hw2b = bf16((h1 @ W2) * dinv[row])   (xsb region is dead now)
    {
        dim3 grid((N + 127) / 128, NCLASS / 64);
        gemm_f32_v2<1, true><<<grid, 256, 0, stream>>>(bufB, W2, hw2b, dinv, N, NHID1, NCLASS);
    }

    // 7. gather layer 2: h2 = relu(dinv[c]*(agg + self) + b2), f32 (bufB region dead after GEMM2)
    {
        long threads = (long)N * (NCLASS / 8);
        gather_agg_bf<NCLASS, true><<<(threads + 255) / 256, 256, 0, stream>>>(
            hw2b, edges, starts, cnt, dinv, b2, h2, N);
    }

    // 8. pool
    hipMemsetAsync(pooled, 0, NUM_GRAPHS * NCLASS * sizeof(float), stream);
    {
        int blocks = (N + POOL_CHUNK - 1) / POOL_CHUNK;
        pool_kernel<<<blocks, 64, 0, stream>>>(h2, batch, pooled, N);
    }

    // 9. head
    head_kernel<<<1, 256, 0, stream>>>(pooled, l1w, l1b, l2w, l2b, out);
}

// Round 8
// 552.594 us; speedup vs baseline: 8.8574x; 1.1542x over previous
//
#include <hip/hip_runtime.h>
#include <hip/hip_bf16.h>
#include <math.h>

#define N_NODES 100000
#define N_EDGES 1600000
#define NFEAT 256
#define NHID1 128
#define NCLASS 64
#define NUM_GRAPHS 64

#define SCAN_CHUNK 1024
#define SCAN_NB ((N_NODES + SCAN_CHUNK - 1) / SCAN_CHUNK)
#define POOL_CHUNK 64

typedef __attribute__((ext_vector_type(8))) short bf16x8;
typedef __attribute__((ext_vector_type(4))) float f32x4;

// ---------------- bf16 helpers (bit-level, RNE) ----------------

__device__ __forceinline__ unsigned short f2bf(float f) {
    unsigned u = __float_as_uint(f);
    u += 0x7fffu + ((u >> 16) & 1u);   // round to nearest even
    return (unsigned short)(u >> 16);
}
__device__ __forceinline__ unsigned packbf2(float lo, float hi) {
    return (unsigned)f2bf(lo) | ((unsigned)f2bf(hi) << 16);
}
__device__ __forceinline__ float bflo(unsigned p) { return __uint_as_float(p << 16); }
__device__ __forceinline__ float bfhi(unsigned p) { return __uint_as_float(p & 0xffff0000u); }

// ---------------- pass 1: packed count+degree (ONE u64 atomic per edge) ----------------

__global__ void count_deg_kernel(const int* __restrict__ cols,
                                 const float* __restrict__ w,
                                 unsigned long long* __restrict__ packed, int nE) {
    int e = blockIdx.x * blockDim.x + threadIdx.x;
    if (e < nE) {
        int c = cols[e];
        unsigned long long fix = (unsigned long long)((double)w[e] * 4294967296.0 + 0.5);
        atomicAdd(&packed[c], (1ULL << 52) | fix);
    }
}

__global__ void decode_kernel(const unsigned long long* __restrict__ packed,
                              int* __restrict__ cnt,
                              float* __restrict__ dinv, int n) {
    int i = blockIdx.x * blockDim.x + threadIdx.x;
    if (i < n) {
        unsigned long long p = packed[i];
        cnt[i] = (int)(p >> 52);
        double degw = (double)(p & ((1ULL << 52) - 1)) * (1.0 / 4294967296.0);
        float deg = (float)(1.0 + degw);
        dinv[i] = rsqrtf(deg);
    }
}

// ---------------- prefix scan (3 kernels) ----------------

__global__ __launch_bounds__(256) void scan_reduce_kernel(const int* __restrict__ cnt,
                                                          int* __restrict__ bsums, int n) {
    __shared__ int sdata[256];
    int b = blockIdx.x, t = threadIdx.x;
    int base = b * SCAN_CHUNK + t * 4;
    int s = 0;
    #pragma unroll
    for (int i = 0; i < 4; i++) {
        int idx = base + i;
        if (idx < n) s += cnt[idx];
    }
    sdata[t] = s;
    __syncthreads();
    for (int off = 128; off > 0; off >>= 1) {
        if (t < off) sdata[t] += sdata[t + off];
        __syncthreads();
    }
    if (t == 0) bsums[b] = sdata[0];
}

__global__ void scan_top_kernel(const int* __restrict__ bsums, int* __restrict__ boff, int nb) {
    if (threadIdx.x == 0 && blockIdx.x == 0) {
        int acc = 0;
        for (int i = 0; i < nb; i++) {
            boff[i] = acc;
            acc += bsums[i];
        }
    }
}

__global__ __launch_bounds__(256) void scan_final_kernel(const int* __restrict__ cnt,
                                                         const int* __restrict__ boff,
                                                         int* __restrict__ starts,
                                                         int* __restrict__ cursor, int n) {
    __shared__ int sdata[256];
    int b = blockIdx.x, t = threadIdx.x;
    int base = b * SCAN_CHUNK + t * 4;
    int v[4];
    int s = 0;
    #pragma unroll
    for (int i = 0; i < 4; i++) {
        int idx = base + i;
        v[i] = (idx < n) ? cnt[idx] : 0;
        s += v[i];
    }
    sdata[t] = s;
    __syncthreads();
    for (int off = 1; off < 256; off <<= 1) {
        int add = (t >= off) ? sdata[t - off] : 0;
        __syncthreads();
        sdata[t] += add;
        __syncthreads();
    }
    int run = sdata[t] - s + boff[b];
    #pragma unroll
    for (int i = 0; i < 4; i++) {
        int idx = base + i;
        if (idx < n) {
            starts[idx] = run;
            cursor[idx] = run;
        }
        run += v[i];
    }
}

// ---------------- fill CSC: one 8B store per edge ----------------

__global__ void fill_kernel(const int* __restrict__ rows,
                            const int* __restrict__ cols,
                            const float* __restrict__ w,
                            int* __restrict__ cursor,
                            int2* __restrict__ edges, int nE) {
    int e = blockIdx.x * blockDim.x + threadIdx.x;
    if (e < nE) {
        int c = cols[e], r = rows[e];
        int pos = atomicAdd(&cursor[c], 1);
        edges[pos] = make_int2(r, __float_as_int(w[e]));
    }
}

// ---------------- weight transpose + bf16 pack: W[K][Nn] f32 -> WT[Nn][K/2] dwords ----------------

__global__ void transpose_bf_kernel(const float* __restrict__ W, unsigned* __restrict__ WT,
                                    int K, int Nn) {
    int idx = blockIdx.x * blockDim.x + threadIdx.x;
    int total = Nn * (K / 2);
    if (idx < total) {
        int n = idx / (K / 2);
        int kp = idx - n * (K / 2);
        WT[idx] = packbf2(W[(2 * kp) * Nn + n], W[(2 * kp + 1) * Nn + n]);
    }
}

// ---------------- MFMA bf16 GEMM: C[M,NT] = A[M,KK] @ BT^T, epilogue *rowscale -> bf16 ----------------
// 128-row block, 4 waves; wave w covers rows w*32 (2 row-tiles of 16), all NT cols (CT col-tiles).
// LDS chunk-plane layout [4][rows][4 dwords]: all b128 LDS ops at the 8-phase floor.
// A: f32 (convert in staging) or packed-bf16. BT: pre-transposed bf16 [NT][KK/2] dwords.

template <int NT, int KK, bool ABF16>
__global__ __launch_bounds__(256) void gemm_mfma(const void* __restrict__ Av,
                                                 const unsigned* __restrict__ BT,
                                                 const float* __restrict__ rowscale,
                                                 unsigned short* __restrict__ C,
                                                 int M) {
    constexpr int CT = NT / 16;
    constexpr int KD = KK / 2;          // dwords per bf16 row
    __shared__ unsigned Al[4][128][4];
    __shared__ unsigned Bl[4][NT][4];
    const int tid = threadIdx.x;
    const int wave = tid >> 6;
    const int lane = tid & 63;
    const int quad = lane >> 4;
    const int l16 = lane & 15;
    const int row0 = blockIdx.x * 128;

    f32x4 acc[2][CT] = {};

    for (int k0 = 0; k0 < KK; k0 += 32) {
        // ---- stage A ----
        if (ABF16) {
            const unsigned* Ab = (const unsigned*)Av;
            #pragma unroll
            for (int i = 0; i < 2; i++) {
                int idx = tid + i * 256;
                int ar = idx >> 2, aq = idx & 3;
                uint4 v = make_uint4(0, 0, 0, 0);
                if (row0 + ar < M)
                    v = *(const uint4*)(Ab + (long)(row0 + ar) * KD + k0 / 2 + aq * 4);
                *(uint4*)&Al[aq][ar][0] = v;
            }
        } else {
            const float* Af = (const float*)Av;
            int ar = tid >> 1, ah = tid & 1;
            float4 v0 = make_float4(0, 0, 0, 0), v1 = v0, v2 = v0, v3 = v0;
            if (row0 + ar < M) {
                const float* p = Af + (long)(row0 + ar) * KK + k0 + ah * 16;
                v0 = *(const float4*)p;
                v1 = *(const float4*)(p + 4);
                v2 = *(const float4*)(p + 8);
                v3 = *(const float4*)(p + 12);
            }
            uint4 d0 = make_uint4(packbf2(v0.x, v0.y), packbf2(v0.z, v0.w),
                                  packbf2(v1.x, v1.y), packbf2(v1.z, v1.w));
            uint4 d1 = make_uint4(packbf2(v2.x, v2.y), packbf2(v2.z, v2.w),
                                  packbf2(v3.x, v3.y), packbf2(v3.z, v3.w));
            *(uint4*)&Al[ah * 2 + 0][ar][0] = d0;
            *(uint4*)&Al[ah * 2 + 1][ar][0] = d1;
        }
        // ---- stage B ----
        #pragma unroll
        for (int i = 0; i < NT / 64; i++) {
            int idx = tid + i * 256;
            int br = idx >> 2, bq = idx & 3;
            *(uint4*)&Bl[bq][br][0] = *(const uint4*)(BT + (long)br * KD + k0 / 2 + bq * 4);
        }
        __syncthreads();

        bf16x8 af[2];
        #pragma unroll
        for (int rt = 0; rt < 2; rt++)
            af[rt] = *(const bf16x8*)&Al[quad][wave * 32 + rt * 16 + l16][0];
        #pragma unroll
        for (int ct = 0; ct < CT; ct++) {
            bf16x8 bfr = *(const bf16x8*)&Bl[quad][ct * 16 + l16][0];
            acc[0][ct] = __builtin_amdgcn_mfma_f32_16x16x32_bf16(af[0], bfr, acc[0][ct], 0, 0, 0);
            acc[1][ct] = __builtin_amdgcn_mfma_f32_16x16x32_bf16(af[1], bfr, acc[1][ct], 0, 0, 0);
        }
        __syncthreads();
    }

    // epilogue: C/D layout col=lane&15, row=quad*4+reg [verified m89/m91]
    #pragma unroll
    for (int rt = 0; rt < 2; rt++) {
        #pragma unroll
        for (int reg = 0; reg < 4; reg++) {
            int row = row0 + wave * 32 + rt * 16 + quad * 4 + reg;
            if (row < M) {
                float sc = rowscale[row];
                unsigned short* cp = C + (long)row * NT + l16;
                #pragma unroll
                for (int ct = 0; ct < CT; ct++)
                    cp[ct * 16] = f2bf(acc[rt][ct][reg] * sc);
            }
        }
    }
}

// ---------------- gather-aggregate over bf16 features ----------------
// out[c] = relu(dinv[c]*(sum_e w_e*xs[r_e] + xs[c]) + b); out f32 or bf16-packed.

template <int F, bool RELU, bool BF16OUT>
__global__ __launch_bounds__(256) void gather_agg_bf(const unsigned* __restrict__ xsb,
                                                     const int2* __restrict__ edges,
                                                     const int* __restrict__ starts,
                                                     const int* __restrict__ cnt,
                                                     const float* __restrict__ dinv,
                                                     const float* __restrict__ bias,
                                                     void* __restrict__ outv, int n) {
    constexpr int G = F / 8;        // lanes per node; each lane covers 8 features
    constexpr int FU = F / 2;       // uints per row
    int gt = blockIdx.x * blockDim.x + threadIdx.x;
    int node = gt / G;
    int lane = gt - node * G;
    if (node >= n) return;

    int s = starts[node];
    int c = cnt[node];
    float acc[8] = {};
    const unsigned* lbase = xsb + lane * 4;
    for (int j = s; j < s + c; j++) {
        int2 ed = edges[j];
        float wv = __int_as_float(ed.y);
        uint4 p = *(const uint4*)(lbase + (long)ed.x * FU);
        acc[0] += bflo(p.x) * wv; acc[1] += bfhi(p.x) * wv;
        acc[2] += bflo(p.y) * wv; acc[3] += bfhi(p.y) * wv;
        acc[4] += bflo(p.z) * wv; acc[5] += bfhi(p.z) * wv;
        acc[6] += bflo(p.w) * wv; acc[7] += bfhi(p.w) * wv;
    }
    float d = dinv[node];
    uint4 sp = *(const uint4*)(lbase + (long)node * FU);
    float sv[8] = { bflo(sp.x), bfhi(sp.x), bflo(sp.y), bfhi(sp.y),
                    bflo(sp.z), bfhi(sp.z), bflo(sp.w), bfhi(sp.w) };
    float4 bb0 = ((const float4*)bias)[lane * 2];
    float4 bb1 = ((const float4*)bias)[lane * 2 + 1];
    float bbv[8] = { bb0.x, bb0.y, bb0.z, bb0.w, bb1.x, bb1.y, bb1.z, bb1.w };
    float r[8];
    #pragma unroll
    for (int i = 0; i < 8; i++) {
        float v = d * (acc[i] + sv[i]) + bbv[i];
        r[i] = RELU ? fmaxf(v, 0.f) : v;
    }
    if (BF16OUT) {
        unsigned* ob = (unsigned*)outv;
        uint4 pk = make_uint4(packbf2(r[0], r[1]), packbf2(r[2], r[3]),
                              packbf2(r[4], r[5]), packbf2(r[6], r[7]));
        *(uint4*)(ob + (long)node * FU + lane * 4) = pk;
    } else {
        float* o = (float*)outv + (long)node * F + lane * 8;
        *(float4*)o       = make_float4(r[0], r[1], r[2], r[3]);
        *(float4*)(o + 4) = make_float4(r[4], r[5], r[6], r[7]);
    }
}

// ---------------- pooling over sorted batch ----------------

__global__ void pool_kernel(const float* __restrict__ h,
                            const int* __restrict__ batch,
                            float* __restrict__ pooled,
                            int n) {
    int f = threadIdx.x;  // 0..63
    long start = (long)blockIdx.x * POOL_CHUNK;
    long end = start + POOL_CHUNK;
    if (end > n) end = n;
    if (start >= end) return;
    int cur = batch[start];
    float acc = 0.f;
    for (long i = start; i < end; i++) {
        int g = batch[i];
        if (g != cur) {
            atomicAdd(&pooled[cur * NCLASS + f], acc);
            acc = 0.f;
            cur = g;
        }
        acc += h[i * NCLASS + f];
    }
    atomicAdd(&pooled[cur * NCLASS + f], acc);
}

// ---------------- head: 256 threads, all-LDS MLP + log_softmax + argmax ----------------

__global__ __launch_bounds__(256) void head_kernel(const float* __restrict__ pooled,
                                                   const float* __restrict__ l1w,
                                                   const float* __restrict__ l1b,
                                                   const float* __restrict__ l2w,
                                                   const float* __restrict__ l2b,
                                                   float* __restrict__ out) {
    __shared__ float P[64][68];
    __shared__ float W[64][68];
    __shared__ float red0[64][4];
    __shared__ float red1[64][4];
    const int tid = threadIdx.x;

    for (int i = tid; i < 1024; i += 256) {
        int r = i >> 4;
        int cq = (i & 15) * 4;
        *(float4*)&P[r][cq] = *(const float4*)&pooled[r * 64 + cq];
        *(float4*)&W[r][cq] = *(const float4*)&l1w[r * 64 + cq];
    }
    __syncthreads();

    const int g = tid >> 2;
    const int q = tid & 3;
    const int j0 = q * 16;

    float hacc[16];
    #pragma unroll
    for (int jj = 0; jj < 16; jj++) hacc[jj] = l1b[j0 + jj];

    for (int c = 0; c < 64; c++) {
        float pv = P[g][c];
        #pragma unroll
        for (int jj = 0; jj < 16; jj += 4) {
            float4 wv = *(const float4*)&W[c][j0 + jj];
            hacc[jj + 0] += pv * wv.x;
            hacc[jj + 1] += pv * wv.y;
            hacc[jj + 2] += pv * wv.z;
            hacc[jj + 3] += pv * wv.w;
        }
    }

    float o0 = 0.f, o1 = 0.f;
    #pragma unroll
    for (int jj = 0; jj < 16; jj++) {
        float h = fmaxf(hacc[jj], 0.f);
        o0 += h * l2w[(j0 + jj) * 2];
        o1 += h * l2w[(j0 + jj) * 2 + 1];
    }
    red0[g][q] = o0;
    red1[g][q] = o1;
    __syncthreads();

    if (q == 0) {
        float a0 = red0[g][0] + red0[g][1] + red0[g][2] + red0[g][3] + l2b[0];
        float a1 = red1[g][0] + red1[g][1] + red1[g][2] + red1[g][3] + l2b[1];
        float m = fmaxf(a0, a1);
        float lse = m + logf(expf(a0 - m) + expf(a1 - m));
        out[g * 2 + 0] = a0 - lse;
        out[g * 2 + 1] = a1 - lse;
        out[128 + g] = (a1 > a0) ? 1.f : 0.f;
        out[192 + g * 2 + 0] = a0;
        out[192 + g * 2 + 1] = a1;
    }
}

// ---------------- launch ----------------

extern "C" void kernel_launch(void* const* d_in, const int* in_sizes, int n_in,
                              void* d_out, int out_size, void* d_ws, size_t ws_size,
                              hipStream_t stream) {
    const float* x   = (const float*)d_in[0];           // [N, 256]
    const int* eidx  = (const int*)d_in[1];             // [2, E] flat
    const float* ew  = (const float*)d_in[2];           // [E]
    const int* batch = (const int*)d_in[3];             // [N]
    const float* W1  = (const float*)d_in[4];           // [256,128]
    const float* b1  = (const float*)d_in[5];
    const float* W2  = (const float*)d_in[6];           // [128,64]
    const float* b2  = (const float*)d_in[7];
    const float* l1w = (const float*)d_in[8];           // [64,64]
    const float* l1b = (const float*)d_in[9];
    const float* l2w = (const float*)d_in[10];          // [64,2]
    const float* l2b = (const float*)d_in[11];
    float* out = (float*)d_out;

    const int N = N_NODES, E = N_EDGES;
    const int* rows = eidx;
    const int* cols = eidx + E;

    // workspace layout (float offsets; 8/16B alignment kept)
    float* ws = (float*)d_ws;
    unsigned long long* packed = (unsigned long long*)ws;   // 2N floats
    float* dinv   = ws + 2 * N;                // N       -> 300000
    int*   cnt    = (int*)(dinv + N);          // N       -> 400000
    int*   starts = cnt + N;                   // N       -> 500000
    int*   cursor = starts + N;                // N       -> 600000
    int*   bsums  = cursor + N;                // 256
    int*   boff   = bsums + 256;               // 256     -> 600512
    unsigned* w1t = (unsigned*)(boff + 256);   // 16384   -> 600512 (16B aligned)
    unsigned* w2t = w1t + 16384;               // 4096    -> 616896
    int2*  edges  = (int2*)(w2t + 4096);       // 2E      -> 620992
    unsigned* xsb = (unsigned*)(edges + E);    // N*64 dw -> 3,820,992 (16B aligned)
    unsigned* h1b = xsb + (long)N * 64;        // N*64 dw -> 10,220,992
    float* pooled = (float*)(h1b + (long)N * 64);  // 4096
    // reuse: hw2b (N*32 dw) in dead xsb; h2 f32 (N*64) in dead h1b region
    unsigned* hw2b = xsb;
    float* h2 = (float*)h1b;

    // 1. packed count+deg (1 atomic/edge), decode
    hipMemsetAsync(packed, 0, N * sizeof(unsigned long long), stream);
    count_deg_kernel<<<(E + 255) / 256, 256, 0, stream>>>(cols, ew, packed, E);
    decode_kernel<<<(N + 255) / 256, 256, 0, stream>>>(packed, cnt, dinv, N);

    // 2. weight prep (independent)
    transpose_bf_kernel<<<64, 256, 0, stream>>>(W1, w1t, NFEAT, NHID1);
    transpose_bf_kernel<<<16, 256, 0, stream>>>(W2, w2t, NHID1, NCLASS);

    // 3. prefix scan of cnt -> starts, cursor
    scan_reduce_kernel<<<SCAN_NB, 256, 0, stream>>>(cnt, bsums, N);
    scan_top_kernel<<<1, 64, 0, stream>>>(bsums, boff, SCAN_NB);
    scan_final_kernel<<<SCAN_NB, 256, 0, stream>>>(cnt, boff, starts, cursor, N);

    // 4. fill CSC edges (r, w)
    fill_kernel<<<(E + 255) / 256, 256, 0, stream>>>(rows, cols, ew, cursor, edges, E);

    // 5. GEMM1 (MFMA): xsb = bf16((x @ W1) * dinv[row])
    gemm_mfma<NHID1, NFEAT, false><<<(N + 127) / 128, 256, 0, stream>>>(
        x, w1t, dinv, (unsigned short*)xsb, N);

    // 6. gather layer 1: h1b = bf16(relu(dinv[c]*(agg + self) + b1))
    {
        long threads = (long)N * (NHID1 / 8);
        gather_agg_bf<NHID1, true, true><<<(threads + 255) / 256, 256, 0, stream>>>(
            xsb, edges, starts, cnt, dinv, b1, h1b, N);
    }

    // 7. GEMM2 (MFMA): hw2b = bf16((h1 @ W2) * dinv[row])  (into dead xsb region)
    gemm_mfma<NCLASS, NHID1, true><<<(N + 127) / 128, 256, 0, stream>>>(
        h1b, w2t, dinv, (unsigned short*)hw2b, N);

    // 8. gather layer 2: h2 = f32 relu(dinv[c]*(agg + self) + b2)  (into dead h1b region)
    {
        long threads = (long)N * (NCLASS / 8);
        gather_agg_bf<NCLASS, true, false><<<(threads + 255) / 256, 256, 0, stream>>>(
            hw2b, edges, starts, cnt, dinv, b2, h2, N);
    }

    // 9. pool
    hipMemsetAsync(pooled, 0, NUM_GRAPHS * NCLASS * sizeof(float), stream);
    {
        int blocks = (N + POOL_CHUNK - 1) / POOL_CHUNK;
        pool_kernel<<<blocks, 64, 0, stream>>>(h2, batch, pooled, N);
    }

    // 10. head
    head_kernel<<<1, 256, 0, stream>>>(pooled, l1w, l1b, l2w, l2b, out);
}

// Round 9
// 437.961 us; speedup vs baseline: 11.1758x; 1.2617x over previous
//
#include <hip/hip_runtime.h>
#include <hip/hip_bf16.h>
#include <math.h>

#define N_NODES 100000
#define N_EDGES 1600000
#define NFEAT 256
#define NHID1 128
#define NCLASS 64
#define NUM_GRAPHS 64

#define POOL_CHUNK 64

// bucket geometry: bucket = col >> 8 (256 nodes per bucket)
#define NBUCK 391                    // ceil(100000/256)
#define EPB 8192                     // edges per block in binning passes
#define NBLK_A 196                   // ceil(1600000/8192)

typedef __attribute__((ext_vector_type(8))) short bf16x8;
typedef __attribute__((ext_vector_type(4))) float f32x4;

// ---------------- bf16 helpers (bit-level, RNE) ----------------

__device__ __forceinline__ unsigned short f2bf(float f) {
    unsigned u = __float_as_uint(f);
    u += 0x7fffu + ((u >> 16) & 1u);   // round to nearest even
    return (unsigned short)(u >> 16);
}
__device__ __forceinline__ unsigned packbf2(float lo, float hi) {
    return (unsigned)f2bf(lo) | ((unsigned)f2bf(hi) << 16);
}
__device__ __forceinline__ float bflo(unsigned p) { return __uint_as_float(p << 16); }
__device__ __forceinline__ float bfhi(unsigned p) { return __uint_as_float(p & 0xffff0000u); }

// ---------------- pass A1: bucket histogram (block-aggregated atomics) ----------------

__global__ __launch_bounds__(256) void hist_kernel(const int* __restrict__ cols,
                                                   int* __restrict__ ghist, int nE) {
    __shared__ int h[NBUCK];
    const int tid = threadIdx.x;
    for (int i = tid; i < NBUCK; i += 256) h[i] = 0;
    __syncthreads();
    long base = (long)blockIdx.x * EPB;
    for (int j = tid; j < EPB; j += 256) {
        long idx = base + j;
        if (idx < nE) atomicAdd(&h[cols[idx] >> 8], 1);
    }
    __syncthreads();
    for (int i = tid; i < NBUCK; i += 256) {
        int v = h[i];
        if (v) atomicAdd(&ghist[i], v);
    }
}

// ---------------- bucket scan: 391 entries -> gbase, gcursor ----------------

__global__ __launch_bounds__(512) void bucket_scan_kernel(const int* __restrict__ ghist,
                                                          int* __restrict__ gbase,
                                                          int* __restrict__ gcursor) {
    __shared__ int sh[512];
    int t = threadIdx.x;
    int v = (t < NBUCK) ? ghist[t] : 0;
    sh[t] = v;
    __syncthreads();
    for (int off = 1; off < 512; off <<= 1) {
        int add = (t >= off) ? sh[t - off] : 0;
        __syncthreads();
        sh[t] += add;
        __syncthreads();
    }
    if (t < NBUCK) {
        int excl = sh[t] - v;
        gbase[t] = excl;
        gcursor[t] = excl;
    }
}

// ---------------- pass A2: scatter edges into bucket-grouped csc_tmp ----------------
// record: .x = r | ((col&255)<<17), .y = w bits

__global__ __launch_bounds__(256) void scatter_bucket_kernel(const int* __restrict__ rows,
                                                             const int* __restrict__ cols,
                                                             const float* __restrict__ w,
                                                             int* __restrict__ gcursor,
                                                             int2* __restrict__ csc_tmp, int nE) {
    __shared__ int h[NBUCK];
    __shared__ int bb[NBUCK];
    __shared__ unsigned short rk[EPB];
    const int tid = threadIdx.x;
    for (int i = tid; i < NBUCK; i += 256) h[i] = 0;
    __syncthreads();
    long base = (long)blockIdx.x * EPB;
    for (int j = tid; j < EPB; j += 256) {
        long idx = base + j;
        if (idx < nE) rk[j] = (unsigned short)atomicAdd(&h[cols[idx] >> 8], 1);
    }
    __syncthreads();
    for (int i = tid; i < NBUCK; i += 256) {
        int v = h[i];
        if (v) bb[i] = atomicAdd(&gcursor[i], v);
    }
    __syncthreads();
    for (int j = tid; j < EPB; j += 256) {
        long idx = base + j;
        if (idx < nE) {
            int c = cols[idx];
            int b = c >> 8;
            int pos = bb[b] + (int)rk[j];
            csc_tmp[pos] = make_int2((rows[idx] & 0x1FFFF) | ((c & 255) << 17),
                                     __float_as_int(w[idx]));
        }
    }
}

// ---------------- pass B: per-bucket node-level CSC + deg/dinv + starts/cnt ----------------

__global__ __launch_bounds__(256) void build_csc_kernel(const int2* __restrict__ csc_tmp,
                                                        const int* __restrict__ gbase,
                                                        const int* __restrict__ ghist,
                                                        int2* __restrict__ edges,
                                                        int* __restrict__ starts,
                                                        int* __restrict__ cnt,
                                                        float* __restrict__ dinv, int n) {
    __shared__ int ncnt[256];
    __shared__ float nws[256];
    __shared__ int sh[256];
    __shared__ int ncur[256];
    const int tid = threadIdx.x;
    const int b = blockIdx.x;
    const int base = gbase[b];
    const int cntb = ghist[b];

    ncnt[tid] = 0;
    nws[tid] = 0.f;
    __syncthreads();

    // sweep 1: per-node count + weight sum
    for (int i = tid; i < cntb; i += 256) {
        int2 rec = csc_tmp[base + i];
        int local = ((unsigned)rec.x) >> 17;
        atomicAdd(&ncnt[local], 1);
        atomicAdd(&nws[local], __int_as_float(rec.y));
    }
    __syncthreads();

    // exclusive scan over 256 node counts
    int v = ncnt[tid];
    sh[tid] = v;
    __syncthreads();
    for (int off = 1; off < 256; off <<= 1) {
        int add = (tid >= off) ? sh[tid - off] : 0;
        __syncthreads();
        sh[tid] += add;
        __syncthreads();
    }
    int excl = sh[tid] - v;
    ncur[tid] = excl;

    int node = (b << 8) + tid;
    if (node < n) {
        cnt[node] = v;
        starts[node] = base + excl;
        dinv[node] = rsqrtf(1.0f + nws[tid]);
    }
    __syncthreads();

    // sweep 2: place edges at exact node positions
    for (int i = tid; i < cntb; i += 256) {
        int2 rec = csc_tmp[base + i];
        int local = ((unsigned)rec.x) >> 17;
        int r = rec.x & 0x1FFFF;
        int pos = base + atomicAdd(&ncur[local], 1);
        edges[pos] = make_int2(r, rec.y);
    }
}

// ---------------- weight transpose + bf16 pack: W[K][Nn] f32 -> WT[Nn][K/2] dwords ----------------

__global__ void transpose_bf_kernel(const float* __restrict__ W, unsigned* __restrict__ WT,
                                    int K, int Nn) {
    int idx = blockIdx.x * blockDim.x + threadIdx.x;
    int total = Nn * (K / 2);
    if (idx < total) {
        int n = idx / (K / 2);
        int kp = idx - n * (K / 2);
        WT[idx] = packbf2(W[(2 * kp) * Nn + n], W[(2 * kp + 1) * Nn + n]);
    }
}

// ---------------- MFMA bf16 GEMM: C[M,NT] = A[M,KK] @ BT^T, epilogue *rowscale -> bf16 ----------------

template <int NT, int KK, bool ABF16>
__global__ __launch_bounds__(256) void gemm_mfma(const void* __restrict__ Av,
                                                 const unsigned* __restrict__ BT,
                                                 const float* __restrict__ rowscale,
                                                 unsigned short* __restrict__ C,
                                                 int M) {
    constexpr int CT = NT / 16;
    constexpr int KD = KK / 2;          // dwords per bf16 row
    __shared__ unsigned Al[4][128][4];
    __shared__ unsigned Bl[4][NT][4];
    const int tid = threadIdx.x;
    const int wave = tid >> 6;
    const int lane = tid & 63;
    const int quad = lane >> 4;
    const int l16 = lane & 15;
    const int row0 = blockIdx.x * 128;

    f32x4 acc[2][CT] = {};

    for (int k0 = 0; k0 < KK; k0 += 32) {
        // ---- stage A ----
        if (ABF16) {
            const unsigned* Ab = (const unsigned*)Av;
            #pragma unroll
            for (int i = 0; i < 2; i++) {
                int idx = tid + i * 256;
                int ar = idx >> 2, aq = idx & 3;
                uint4 v = make_uint4(0, 0, 0, 0);
                if (row0 + ar < M)
                    v = *(const uint4*)(Ab + (long)(row0 + ar) * KD + k0 / 2 + aq * 4);
                *(uint4*)&Al[aq][ar][0] = v;
            }
        } else {
            const float* Af = (const float*)Av;
            int ar = tid >> 1, ah = tid & 1;
            float4 v0 = make_float4(0, 0, 0, 0), v1 = v0, v2 = v0, v3 = v0;
            if (row0 + ar < M) {
                const float* p = Af + (long)(row0 + ar) * KK + k0 + ah * 16;
                v0 = *(const float4*)p;
                v1 = *(const float4*)(p + 4);
                v2 = *(const float4*)(p + 8);
                v3 = *(const float4*)(p + 12);
            }
            uint4 d0 = make_uint4(packbf2(v0.x, v0.y), packbf2(v0.z, v0.w),
                                  packbf2(v1.x, v1.y), packbf2(v1.z, v1.w));
            uint4 d1 = make_uint4(packbf2(v2.x, v2.y), packbf2(v2.z, v2.w),
                                  packbf2(v3.x, v3.y), packbf2(v3.z, v3.w));
            *(uint4*)&Al[ah * 2 + 0][ar][0] = d0;
            *(uint4*)&Al[ah * 2 + 1][ar][0] = d1;
        }
        // ---- stage B ----
        #pragma unroll
        for (int i = 0; i < NT / 64; i++) {
            int idx = tid + i * 256;
            int br = idx >> 2, bq = idx & 3;
            *(uint4*)&Bl[bq][br][0] = *(const uint4*)(BT + (long)br * KD + k0 / 2 + bq * 4);
        }
        __syncthreads();

        bf16x8 af[2];
        #pragma unroll
        for (int rt = 0; rt < 2; rt++)
            af[rt] = *(const bf16x8*)&Al[quad][wave * 32 + rt * 16 + l16][0];
        #pragma unroll
        for (int ct = 0; ct < CT; ct++) {
            bf16x8 bfr = *(const bf16x8*)&Bl[quad][ct * 16 + l16][0];
            acc[0][ct] = __builtin_amdgcn_mfma_f32_16x16x32_bf16(af[0], bfr, acc[0][ct], 0, 0, 0);
            acc[1][ct] = __builtin_amdgcn_mfma_f32_16x16x32_bf16(af[1], bfr, acc[1][ct], 0, 0, 0);
        }
        __syncthreads();
    }

    // epilogue: C/D layout col=lane&15, row=quad*4+reg
    #pragma unroll
    for (int rt = 0; rt < 2; rt++) {
        #pragma unroll
        for (int reg = 0; reg < 4; reg++) {
            int row = row0 + wave * 32 + rt * 16 + quad * 4 + reg;
            if (row < M) {
                float sc = rowscale[row];
                unsigned short* cp = C + (long)row * NT + l16;
                #pragma unroll
                for (int ct = 0; ct < CT; ct++)
                    cp[ct * 16] = f2bf(acc[rt][ct][reg] * sc);
            }
        }
    }
}

// ---------------- gather-aggregate over bf16 features ----------------

template <int F, bool RELU, bool BF16OUT>
__global__ __launch_bounds__(256) void gather_agg_bf(const unsigned* __restrict__ xsb,
                                                     const int2* __restrict__ edges,
                                                     const int* __restrict__ starts,
                                                     const int* __restrict__ cnt,
                                                     const float* __restrict__ dinv,
                                                     const float* __restrict__ bias,
                                                     void* __restrict__ outv, int n) {
    constexpr int G = F / 8;        // lanes per node; each lane covers 8 features
    constexpr int FU = F / 2;       // uints per row
    int gt = blockIdx.x * blockDim.x + threadIdx.x;
    int node = gt / G;
    int lane = gt - node * G;
    if (node >= n) return;

    int s = starts[node];
    int c = cnt[node];
    float acc[8] = {};
    const unsigned* lbase = xsb + lane * 4;
    for (int j = s; j < s + c; j++) {
        int2 ed = edges[j];
        float wv = __int_as_float(ed.y);
        uint4 p = *(const uint4*)(lbase + (long)ed.x * FU);
        acc[0] += bflo(p.x) * wv; acc[1] += bfhi(p.x) * wv;
        acc[2] += bflo(p.y) * wv; acc[3] += bfhi(p.y) * wv;
        acc[4] += bflo(p.z) * wv; acc[5] += bfhi(p.z) * wv;
        acc[6] += bflo(p.w) * wv; acc[7] += bfhi(p.w) * wv;
    }
    float d = dinv[node];
    uint4 sp = *(const uint4*)(lbase + (long)node * FU);
    float sv[8] = { bflo(sp.x), bfhi(sp.x), bflo(sp.y), bfhi(sp.y),
                    bflo(sp.z), bfhi(sp.z), bflo(sp.w), bfhi(sp.w) };
    float4 bb0 = ((const float4*)bias)[lane * 2];
    float4 bb1 = ((const float4*)bias)[lane * 2 + 1];
    float bbv[8] = { bb0.x, bb0.y, bb0.z, bb0.w, bb1.x, bb1.y, bb1.z, bb1.w };
    float r[8];
    #pragma unroll
    for (int i = 0; i < 8; i++) {
        float v = d * (acc[i] + sv[i]) + bbv[i];
        r[i] = RELU ? fmaxf(v, 0.f) : v;
    }
    if (BF16OUT) {
        unsigned* ob = (unsigned*)outv;
        uint4 pk = make_uint4(packbf2(r[0], r[1]), packbf2(r[2], r[3]),
                              packbf2(r[4], r[5]), packbf2(r[6], r[7]));
        *(uint4*)(ob + (long)node * FU + lane * 4) = pk;
    } else {
        float* o = (float*)outv + (long)node * F + lane * 8;
        *(float4*)o       = make_float4(r[0], r[1], r[2], r[3]);
        *(float4*)(o + 4) = make_float4(r[4], r[5], r[6], r[7]);
    }
}

// ---------------- pooling over sorted batch ----------------

__global__ void pool_kernel(const float* __restrict__ h,
                            const int* __restrict__ batch,
                            float* __restrict__ pooled,
                            int n) {
    int f = threadIdx.x;  // 0..63
    long start = (long)blockIdx.x * POOL_CHUNK;
    long end = start + POOL_CHUNK;
    if (end > n) end = n;
    if (start >= end) return;
    int cur = batch[start];
    float acc = 0.f;
    for (long i = start; i < end; i++) {
        int g = batch[i];
        if (g != cur) {
            atomicAdd(&pooled[cur * NCLASS + f], acc);
            acc = 0.f;
            cur = g;
        }
        acc += h[i * NCLASS + f];
    }
    atomicAdd(&pooled[cur * NCLASS + f], acc);
}

// ---------------- head: 256 threads, all-LDS MLP + log_softmax + argmax ----------------

__global__ __launch_bounds__(256) void head_kernel(const float* __restrict__ pooled,
                                                   const float* __restrict__ l1w,
                                                   const float* __restrict__ l1b,
                                                   const float* __restrict__ l2w,
                                                   const float* __restrict__ l2b,
                                                   float* __restrict__ out) {
    __shared__ float P[64][68];
    __shared__ float W[64][68];
    __shared__ float red0[64][4];
    __shared__ float red1[64][4];
    const int tid = threadIdx.x;

    for (int i = tid; i < 1024; i += 256) {
        int r = i >> 4;
        int cq = (i & 15) * 4;
        *(float4*)&P[r][cq] = *(const float4*)&pooled[r * 64 + cq];
        *(float4*)&W[r][cq] = *(const float4*)&l1w[r * 64 + cq];
    }
    __syncthreads();

    const int g = tid >> 2;
    const int q = tid & 3;
    const int j0 = q * 16;

    float hacc[16];
    #pragma unroll
    for (int jj = 0; jj < 16; jj++) hacc[jj] = l1b[j0 + jj];

    for (int c = 0; c < 64; c++) {
        float pv = P[g][c];
        #pragma unroll
        for (int jj = 0; jj < 16; jj += 4) {
            float4 wv = *(const float4*)&W[c][j0 + jj];
            hacc[jj + 0] += pv * wv.x;
            hacc[jj + 1] += pv * wv.y;
            hacc[jj + 2] += pv * wv.z;
            hacc[jj + 3] += pv * wv.w;
        }
    }

    float o0 = 0.f, o1 = 0.f;
    #pragma unroll
    for (int jj = 0; jj < 16; jj++) {
        float h = fmaxf(hacc[jj], 0.f);
        o0 += h * l2w[(j0 + jj) * 2];
        o1 += h * l2w[(j0 + jj) * 2 + 1];
    }
    red0[g][q] = o0;
    red1[g][q] = o1;
    __syncthreads();

    if (q == 0) {
        float a0 = red0[g][0] + red0[g][1] + red0[g][2] + red0[g][3] + l2b[0];
        float a1 = red1[g][0] + red1[g][1] + red1[g][2] + red1[g][3] + l2b[1];
        float m = fmaxf(a0, a1);
        float lse = m + logf(expf(a0 - m) + expf(a1 - m));
        out[g * 2 + 0] = a0 - lse;
        out[g * 2 + 1] = a1 - lse;
        out[128 + g] = (a1 > a0) ? 1.f : 0.f;
        out[192 + g * 2 + 0] = a0;
        out[192 + g * 2 + 1] = a1;
    }
}

// ---------------- launch ----------------

extern "C" void kernel_launch(void* const* d_in, const int* in_sizes, int n_in,
                              void* d_out, int out_size, void* d_ws, size_t ws_size,
                              hipStream_t stream) {
    const float* x   = (const float*)d_in[0];           // [N, 256]
    const int* eidx  = (const int*)d_in[1];             // [2, E] flat
    const float* ew  = (const float*)d_in[2];           // [E]
    const int* batch = (const int*)d_in[3];             // [N]
    const float* W1  = (const float*)d_in[4];           // [256,128]
    const float* b1  = (const float*)d_in[5];
    const float* W2  = (const float*)d_in[6];           // [128,64]
    const float* b2  = (const float*)d_in[7];
    const float* l1w = (const float*)d_in[8];           // [64,64]
    const float* l1b = (const float*)d_in[9];
    const float* l2w = (const float*)d_in[10];          // [64,2]
    const float* l2b = (const float*)d_in[11];
    float* out = (float*)d_out;

    const int N = N_NODES, E = N_EDGES;
    const int* rows = eidx;
    const int* cols = eidx + E;

    // workspace layout (float offsets; 16B alignment for vector arrays)
    float* ws = (float*)d_ws;
    int*   ghist   = (int*)ws;                  // 391   -> pad to 512
    int*   gbase   = ghist + 512;               // 391   -> pad to 512
    int*   gcursor = gbase + 512;               // 391   -> pad to 512
    float* dinv    = (float*)(gcursor + 512);   // N
    int*   cnt     = (int*)(dinv + N);          // N
    int*   starts  = cnt + N;                   // N
    unsigned* w1t  = (unsigned*)(starts + N);   // 16384
    unsigned* w2t  = w1t + 16384;               // 4096
    int2*  csc_tmp = (int2*)(w2t + 4096);       // E int2 (16B-aligned)
    int2*  edges   = csc_tmp + E;               // E int2
    unsigned* xsb  = (unsigned*)(edges + E);    // N*64 dw
    unsigned* h1b  = xsb + (long)N * 64;        // N*64 dw
    float* pooled  = (float*)(h1b + (long)N * 64);  // 4096
    unsigned* hw2b = xsb;                       // reuse dead xsb: N*32 dw
    float* h2 = (float*)h1b;                    // reuse dead h1b: N*64 f32

    // 1. bucket histogram (block-aggregated atomics)
    hipMemsetAsync(ghist, 0, 512 * sizeof(int), stream);
    hist_kernel<<<NBLK_A, 256, 0, stream>>>(cols, ghist, E);

    // 2. bucket scan
    bucket_scan_kernel<<<1, 512, 0, stream>>>(ghist, gbase, gcursor);

    // 3. scatter into bucket-grouped tmp
    scatter_bucket_kernel<<<NBLK_A, 256, 0, stream>>>(rows, cols, ew, gcursor, csc_tmp, E);

    // 4. per-bucket node-level CSC + deg/dinv/starts/cnt (replaces count_deg+scan+fill)
    build_csc_kernel<<<NBUCK, 256, 0, stream>>>(csc_tmp, gbase, ghist, edges, starts, cnt, dinv, N);

    // 5. weight prep
    transpose_bf_kernel<<<64, 256, 0, stream>>>(W1, w1t, NFEAT, NHID1);
    transpose_bf_kernel<<<16, 256, 0, stream>>>(W2, w2t, NHID1, NCLASS);

    // 6. GEMM1 (MFMA): xsb = bf16((x @ W1) * dinv[row])
    gemm_mfma<NHID1, NFEAT, false><<<(N + 127) / 128, 256, 0, stream>>>(
        x, w1t, dinv, (unsigned short*)xsb, N);

    // 7. gather layer 1: h1b = bf16(relu(dinv[c]*(agg + self) + b1))
    {
        long threads = (long)N * (NHID1 / 8);
        gather_agg_bf<NHID1, true, true><<<(threads + 255) / 256, 256, 0, stream>>>(
            xsb, edges, starts, cnt, dinv, b1, h1b, N);
    }

    // 8. GEMM2 (MFMA): hw2b = bf16((h1 @ W2) * dinv[row])  (into dead xsb region)
    gemm_mfma<NCLASS, NHID1, true><<<(N + 127) / 128, 256, 0, stream>>>(
        h1b, w2t, dinv, (unsigned short*)hw2b, N);

    // 9. gather layer 2: h2 = f32 relu(dinv[c]*(agg + self) + b2)  (into dead h1b region)
    {
        long threads = (long)N * (NCLASS / 8);
        gather_agg_bf<NCLASS, true, false><<<(threads + 255) / 256, 256, 0, stream>>>(
            hw2b, edges, starts, cnt, dinv, b2, h2, N);
    }

    // 10. pool
    hipMemsetAsync(pooled, 0, NUM_GRAPHS * NCLASS * sizeof(float), stream);
    {
        int blocks = (N + POOL_CHUNK - 1) / POOL_CHUNK;
        pool_kernel<<<blocks, 64, 0, stream>>>(h2, batch, pooled, N);
    }

    // 11. head
    head_kernel<<<1, 256, 0, stream>>>(pooled, l1w, l1b, l2w, l2b, out);
}

// Round 10
// 416.413 us; speedup vs baseline: 11.7541x; 1.0517x over previous
//
#include <hip/hip_runtime.h>
#include <hip/hip_bf16.h>
#include <math.h>

#define N_NODES 100000
#define N_EDGES 1600000
#define NFEAT 256
#define NHID1 128
#define NCLASS 64
#define NUM_GRAPHS 64

#define POOL_CHUNK 64

// bucket geometry: bucket = col >> 8 (256 nodes per bucket)
#define NBUCK 391                    // ceil(100000/256)
#define EPB 8192                     // edges per block in binning passes
#define NBLK_A 196                   // ceil(1600000/8192)

typedef __attribute__((ext_vector_type(8))) short bf16x8;
typedef __attribute__((ext_vector_type(4))) float f32x4;

// ---------------- bf16 helpers (bit-level, RNE) ----------------

__device__ __forceinline__ unsigned short f2bf(float f) {
    unsigned u = __float_as_uint(f);
    u += 0x7fffu + ((u >> 16) & 1u);   // round to nearest even
    return (unsigned short)(u >> 16);
}
__device__ __forceinline__ unsigned packbf2(float lo, float hi) {
    return (unsigned)f2bf(lo) | ((unsigned)f2bf(hi) << 16);
}
__device__ __forceinline__ float bflo(unsigned p) { return __uint_as_float(p << 16); }
__device__ __forceinline__ float bfhi(unsigned p) { return __uint_as_float(p & 0xffff0000u); }

// ---------------- pass A1: bucket histogram (block-aggregated atomics) ----------------

__global__ __launch_bounds__(256) void hist_kernel(const int* __restrict__ cols,
                                                   int* __restrict__ ghist, int nE) {
    __shared__ int h[NBUCK];
    const int tid = threadIdx.x;
    for (int i = tid; i < NBUCK; i += 256) h[i] = 0;
    __syncthreads();
    long base = (long)blockIdx.x * EPB;
    for (int j = tid; j < EPB; j += 256) {
        long idx = base + j;
        if (idx < nE) atomicAdd(&h[cols[idx] >> 8], 1);
    }
    __syncthreads();
    for (int i = tid; i < NBUCK; i += 256) {
        int v = h[i];
        if (v) atomicAdd(&ghist[i], v);
    }
}

// ---------------- bucket scan: 391 entries -> gbase, gcursor ----------------

__global__ __launch_bounds__(512) void bucket_scan_kernel(const int* __restrict__ ghist,
                                                          int* __restrict__ gbase,
                                                          int* __restrict__ gcursor) {
    __shared__ int sh[512];
    int t = threadIdx.x;
    int v = (t < NBUCK) ? ghist[t] : 0;
    sh[t] = v;
    __syncthreads();
    for (int off = 1; off < 512; off <<= 1) {
        int add = (t >= off) ? sh[t - off] : 0;
        __syncthreads();
        sh[t] += add;
        __syncthreads();
    }
    if (t < NBUCK) {
        int excl = sh[t] - v;
        gbase[t] = excl;
        gcursor[t] = excl;
    }
}

// ---------------- pass A2: scatter edges into bucket-grouped csc_tmp ----------------
// record: .x = r | ((col&255)<<17), .y = w bits

__global__ __launch_bounds__(256) void scatter_bucket_kernel(const int* __restrict__ rows,
                                                             const int* __restrict__ cols,
                                                             const float* __restrict__ w,
                                                             int* __restrict__ gcursor,
                                                             int2* __restrict__ csc_tmp, int nE) {
    __shared__ int h[NBUCK];
    __shared__ int bb[NBUCK];
    __shared__ unsigned short rk[EPB];
    const int tid = threadIdx.x;
    for (int i = tid; i < NBUCK; i += 256) h[i] = 0;
    __syncthreads();
    long base = (long)blockIdx.x * EPB;
    for (int j = tid; j < EPB; j += 256) {
        long idx = base + j;
        if (idx < nE) rk[j] = (unsigned short)atomicAdd(&h[cols[idx] >> 8], 1);
    }
    __syncthreads();
    for (int i = tid; i < NBUCK; i += 256) {
        int v = h[i];
        if (v) bb[i] = atomicAdd(&gcursor[i], v);
    }
    __syncthreads();
    for (int j = tid; j < EPB; j += 256) {
        long idx = base + j;
        if (idx < nE) {
            int c = cols[idx];
            int b = c >> 8;
            int pos = bb[b] + (int)rk[j];
            csc_tmp[pos] = make_int2((rows[idx] & 0x1FFFF) | ((c & 255) << 17),
                                     __float_as_int(w[idx]));
        }
    }
}

// ---------------- pass B: per-bucket node-level CSC + deg/dinv + starts/cnt ----------------

__global__ __launch_bounds__(256) void build_csc_kernel(const int2* __restrict__ csc_tmp,
                                                        const int* __restrict__ gbase,
                                                        const int* __restrict__ ghist,
                                                        int2* __restrict__ edges,
                                                        int* __restrict__ starts,
                                                        int* __restrict__ cnt,
                                                        float* __restrict__ dinv, int n) {
    __shared__ int ncnt[256];
    __shared__ float nws[256];
    __shared__ int sh[256];
    __shared__ int ncur[256];
    const int tid = threadIdx.x;
    const int b = blockIdx.x;
    const int base = gbase[b];
    const int cntb = ghist[b];

    ncnt[tid] = 0;
    nws[tid] = 0.f;
    __syncthreads();

    // sweep 1: per-node count + weight sum
    for (int i = tid; i < cntb; i += 256) {
        int2 rec = csc_tmp[base + i];
        int local = ((unsigned)rec.x) >> 17;
        atomicAdd(&ncnt[local], 1);
        atomicAdd(&nws[local], __int_as_float(rec.y));
    }
    __syncthreads();

    // exclusive scan over 256 node counts
    int v = ncnt[tid];
    sh[tid] = v;
    __syncthreads();
    for (int off = 1; off < 256; off <<= 1) {
        int add = (tid >= off) ? sh[tid - off] : 0;
        __syncthreads();
        sh[tid] += add;
        __syncthreads();
    }
    int excl = sh[tid] - v;
    ncur[tid] = excl;

    int node = (b << 8) + tid;
    if (node < n) {
        cnt[node] = v;
        starts[node] = base + excl;
        dinv[node] = rsqrtf(1.0f + nws[tid]);
    }
    __syncthreads();

    // sweep 2: place edges at exact node positions
    for (int i = tid; i < cntb; i += 256) {
        int2 rec = csc_tmp[base + i];
        int local = ((unsigned)rec.x) >> 17;
        int r = rec.x & 0x1FFFF;
        int pos = base + atomicAdd(&ncur[local], 1);
        edges[pos] = make_int2(r, rec.y);
    }
}

// ---------------- weight transpose + bf16 pack: W[K][Nn] f32 -> WT[Nn][K/2] dwords ----------------

__global__ void transpose_bf_kernel(const float* __restrict__ W, unsigned* __restrict__ WT,
                                    int K, int Nn) {
    int idx = blockIdx.x * blockDim.x + threadIdx.x;
    int total = Nn * (K / 2);
    if (idx < total) {
        int n = idx / (K / 2);
        int kp = idx - n * (K / 2);
        WT[idx] = packbf2(W[(2 * kp) * Nn + n], W[(2 * kp + 1) * Nn + n]);
    }
}

// ---------------- MFMA bf16 GEMM: C[M,NT] = A[M,KK] @ BT^T, epilogue *rowscale -> bf16 ----------------

template <int NT, int KK, bool ABF16>
__global__ __launch_bounds__(256) void gemm_mfma(const void* __restrict__ Av,
                                                 const unsigned* __restrict__ BT,
                                                 const float* __restrict__ rowscale,
                                                 unsigned short* __restrict__ C,
                                                 int M) {
    constexpr int CT = NT / 16;
    constexpr int KD = KK / 2;          // dwords per bf16 row
    __shared__ unsigned Al[4][128][4];
    __shared__ unsigned Bl[4][NT][4];
    const int tid = threadIdx.x;
    const int wave = tid >> 6;
    const int lane = tid & 63;
    const int quad = lane >> 4;
    const int l16 = lane & 15;
    const int row0 = blockIdx.x * 128;

    f32x4 acc[2][CT] = {};

    for (int k0 = 0; k0 < KK; k0 += 32) {
        // ---- stage A ----
        if (ABF16) {
            const unsigned* Ab = (const unsigned*)Av;
            #pragma unroll
            for (int i = 0; i < 2; i++) {
                int idx = tid + i * 256;
                int ar = idx >> 2, aq = idx & 3;
                uint4 v = make_uint4(0, 0, 0, 0);
                if (row0 + ar < M)
                    v = *(const uint4*)(Ab + (long)(row0 + ar) * KD + k0 / 2 + aq * 4);
                *(uint4*)&Al[aq][ar][0] = v;
            }
        } else {
            const float* Af = (const float*)Av;
            int ar = tid >> 1, ah = tid & 1;
            float4 v0 = make_float4(0, 0, 0, 0), v1 = v0, v2 = v0, v3 = v0;
            if (row0 + ar < M) {
                const float* p = Af + (long)(row0 + ar) * KK + k0 + ah * 16;
                v0 = *(const float4*)p;
                v1 = *(const float4*)(p + 4);
                v2 = *(const float4*)(p + 8);
                v3 = *(const float4*)(p + 12);
            }
            uint4 d0 = make_uint4(packbf2(v0.x, v0.y), packbf2(v0.z, v0.w),
                                  packbf2(v1.x, v1.y), packbf2(v1.z, v1.w));
            uint4 d1 = make_uint4(packbf2(v2.x, v2.y), packbf2(v2.z, v2.w),
                                  packbf2(v3.x, v3.y), packbf2(v3.z, v3.w));
            *(uint4*)&Al[ah * 2 + 0][ar][0] = d0;
            *(uint4*)&Al[ah * 2 + 1][ar][0] = d1;
        }
        // ---- stage B ----
        #pragma unroll
        for (int i = 0; i < NT / 64; i++) {
            int idx = tid + i * 256;
            int br = idx >> 2, bq = idx & 3;
            *(uint4*)&Bl[bq][br][0] = *(const uint4*)(BT + (long)br * KD + k0 / 2 + bq * 4);
        }
        __syncthreads();

        bf16x8 af[2];
        #pragma unroll
        for (int rt = 0; rt < 2; rt++)
            af[rt] = *(const bf16x8*)&Al[quad][wave * 32 + rt * 16 + l16][0];
        #pragma unroll
        for (int ct = 0; ct < CT; ct++) {
            bf16x8 bfr = *(const bf16x8*)&Bl[quad][ct * 16 + l16][0];
            acc[0][ct] = __builtin_amdgcn_mfma_f32_16x16x32_bf16(af[0], bfr, acc[0][ct], 0, 0, 0);
            acc[1][ct] = __builtin_amdgcn_mfma_f32_16x16x32_bf16(af[1], bfr, acc[1][ct], 0, 0, 0);
        }
        __syncthreads();
    }

    // epilogue: C/D layout col=lane&15, row=quad*4+reg
    #pragma unroll
    for (int rt = 0; rt < 2; rt++) {
        #pragma unroll
        for (int reg = 0; reg < 4; reg++) {
            int row = row0 + wave * 32 + rt * 16 + quad * 4 + reg;
            if (row < M) {
                float sc = rowscale[row];
                unsigned short* cp = C + (long)row * NT + l16;
                #pragma unroll
                for (int ct = 0; ct < CT; ct++)
                    cp[ct * 16] = f2bf(acc[rt][ct][reg] * sc);
            }
        }
    }
}

// ---------------- gather-aggregate over bf16 features (4x unrolled for MLP) ----------------

template <int F, bool RELU, bool BF16OUT>
__global__ __launch_bounds__(256) void gather_agg_bf(const unsigned* __restrict__ xsb,
                                                     const int2* __restrict__ edges,
                                                     const int* __restrict__ starts,
                                                     const int* __restrict__ cnt,
                                                     const float* __restrict__ dinv,
                                                     const float* __restrict__ bias,
                                                     void* __restrict__ outv, int n) {
    constexpr int G = F / 8;        // lanes per node; each lane covers 8 features
    constexpr int FU = F / 2;       // uints per row
    int gt = blockIdx.x * blockDim.x + threadIdx.x;
    int node = gt / G;
    int lane = gt - node * G;
    if (node >= n) return;

    int s = starts[node];
    int c = cnt[node];
    int e = s + c;
    float acc[8] = {};
    const unsigned* lbase = xsb + lane * 4;

    int j = s;
    // unroll 4: batch edge-record loads, then 4 independent gathers in flight
    for (; j + 3 < e; j += 4) {
        int2 e0 = edges[j];
        int2 e1 = edges[j + 1];
        int2 e2 = edges[j + 2];
        int2 e3 = edges[j + 3];
        uint4 p0 = *(const uint4*)(lbase + (long)e0.x * FU);
        uint4 p1 = *(const uint4*)(lbase + (long)e1.x * FU);
        uint4 p2 = *(const uint4*)(lbase + (long)e2.x * FU);
        uint4 p3 = *(const uint4*)(lbase + (long)e3.x * FU);
        float w0 = __int_as_float(e0.y);
        float w1 = __int_as_float(e1.y);
        float w2 = __int_as_float(e2.y);
        float w3 = __int_as_float(e3.y);
        acc[0] += bflo(p0.x) * w0; acc[1] += bfhi(p0.x) * w0;
        acc[2] += bflo(p0.y) * w0; acc[3] += bfhi(p0.y) * w0;
        acc[4] += bflo(p0.z) * w0; acc[5] += bfhi(p0.z) * w0;
        acc[6] += bflo(p0.w) * w0; acc[7] += bfhi(p0.w) * w0;
        acc[0] += bflo(p1.x) * w1; acc[1] += bfhi(p1.x) * w1;
        acc[2] += bflo(p1.y) * w1; acc[3] += bfhi(p1.y) * w1;
        acc[4] += bflo(p1.z) * w1; acc[5] += bfhi(p1.z) * w1;
        acc[6] += bflo(p1.w) * w1; acc[7] += bfhi(p1.w) * w1;
        acc[0] += bflo(p2.x) * w2; acc[1] += bfhi(p2.x) * w2;
        acc[2] += bflo(p2.y) * w2; acc[3] += bfhi(p2.y) * w2;
        acc[4] += bflo(p2.z) * w2; acc[5] += bfhi(p2.z) * w2;
        acc[6] += bflo(p2.w) * w2; acc[7] += bfhi(p2.w) * w2;
        acc[0] += bflo(p3.x) * w3; acc[1] += bfhi(p3.x) * w3;
        acc[2] += bflo(p3.y) * w3; acc[3] += bfhi(p3.y) * w3;
        acc[4] += bflo(p3.z) * w3; acc[5] += bfhi(p3.z) * w3;
        acc[6] += bflo(p3.w) * w3; acc[7] += bfhi(p3.w) * w3;
    }
    for (; j < e; j++) {
        int2 ed = edges[j];
        float wv = __int_as_float(ed.y);
        uint4 p = *(const uint4*)(lbase + (long)ed.x * FU);
        acc[0] += bflo(p.x) * wv; acc[1] += bfhi(p.x) * wv;
        acc[2] += bflo(p.y) * wv; acc[3] += bfhi(p.y) * wv;
        acc[4] += bflo(p.z) * wv; acc[5] += bfhi(p.z) * wv;
        acc[6] += bflo(p.w) * wv; acc[7] += bfhi(p.w) * wv;
    }

    float d = dinv[node];
    uint4 sp = *(const uint4*)(lbase + (long)node * FU);
    float sv[8] = { bflo(sp.x), bfhi(sp.x), bflo(sp.y), bfhi(sp.y),
                    bflo(sp.z), bfhi(sp.z), bflo(sp.w), bfhi(sp.w) };
    float4 bb0 = ((const float4*)bias)[lane * 2];
    float4 bb1 = ((const float4*)bias)[lane * 2 + 1];
    float bbv[8] = { bb0.x, bb0.y, bb0.z, bb0.w, bb1.x, bb1.y, bb1.z, bb1.w };
    float r[8];
    #pragma unroll
    for (int i = 0; i < 8; i++) {
        float v = d * (acc[i] + sv[i]) + bbv[i];
        r[i] = RELU ? fmaxf(v, 0.f) : v;
    }
    if (BF16OUT) {
        unsigned* ob = (unsigned*)outv;
        uint4 pk = make_uint4(packbf2(r[0], r[1]), packbf2(r[2], r[3]),
                              packbf2(r[4], r[5]), packbf2(r[6], r[7]));
        *(uint4*)(ob + (long)node * FU + lane * 4) = pk;
    } else {
        float* o = (float*)outv + (long)node * F + lane * 8;
        *(float4*)o       = make_float4(r[0], r[1], r[2], r[3]);
        *(float4*)(o + 4) = make_float4(r[4], r[5], r[6], r[7]);
    }
}

// ---------------- pooling over sorted batch ----------------

__global__ void pool_kernel(const float* __restrict__ h,
                            const int* __restrict__ batch,
                            float* __restrict__ pooled,
                            int n) {
    int f = threadIdx.x;  // 0..63
    long start = (long)blockIdx.x * POOL_CHUNK;
    long end = start + POOL_CHUNK;
    if (end > n) end = n;
    if (start >= end) return;
    int cur = batch[start];
    float acc = 0.f;
    for (long i = start; i < end; i++) {
        int g = batch[i];
        if (g != cur) {
            atomicAdd(&pooled[cur * NCLASS + f], acc);
            acc = 0.f;
            cur = g;
        }
        acc += h[i * NCLASS + f];
    }
    atomicAdd(&pooled[cur * NCLASS + f], acc);
}

// ---------------- head: 256 threads, all-LDS MLP + log_softmax + argmax ----------------

__global__ __launch_bounds__(256) void head_kernel(const float* __restrict__ pooled,
                                                   const float* __restrict__ l1w,
                                                   const float* __restrict__ l1b,
                                                   const float* __restrict__ l2w,
                                                   const float* __restrict__ l2b,
                                                   float* __restrict__ out) {
    __shared__ float P[64][68];
    __shared__ float W[64][68];
    __shared__ float red0[64][4];
    __shared__ float red1[64][4];
    const int tid = threadIdx.x;

    for (int i = tid; i < 1024; i += 256) {
        int r = i >> 4;
        int cq = (i & 15) * 4;
        *(float4*)&P[r][cq] = *(const float4*)&pooled[r * 64 + cq];
        *(float4*)&W[r][cq] = *(const float4*)&l1w[r * 64 + cq];
    }
    __syncthreads();

    const int g = tid >> 2;
    const int q = tid & 3;
    const int j0 = q * 16;

    float hacc[16];
    #pragma unroll
    for (int jj = 0; jj < 16; jj++) hacc[jj] = l1b[j0 + jj];

    for (int c = 0; c < 64; c++) {
        float pv = P[g][c];
        #pragma unroll
        for (int jj = 0; jj < 16; jj += 4) {
            float4 wv = *(const float4*)&W[c][j0 + jj];
            hacc[jj + 0] += pv * wv.x;
            hacc[jj + 1] += pv * wv.y;
            hacc[jj + 2] += pv * wv.z;
            hacc[jj + 3] += pv * wv.w;
        }
    }

    float o0 = 0.f, o1 = 0.f;
    #pragma unroll
    for (int jj = 0; jj < 16; jj++) {
        float h = fmaxf(hacc[jj], 0.f);
        o0 += h * l2w[(j0 + jj) * 2];
        o1 += h * l2w[(j0 + jj) * 2 + 1];
    }
    red0[g][q] = o0;
    red1[g][q] = o1;
    __syncthreads();

    if (q == 0) {
        float a0 = red0[g][0] + red0[g][1] + red0[g][2] + red0[g][3] + l2b[0];
        float a1 = red1[g][0] + red1[g][1] + red1[g][2] + red1[g][3] + l2b[1];
        float m = fmaxf(a0, a1);
        float lse = m + logf(expf(a0 - m) + expf(a1 - m));
        out[g * 2 + 0] = a0 - lse;
        out[g * 2 + 1] = a1 - lse;
        out[128 + g] = (a1 > a0) ? 1.f : 0.f;
        out[192 + g * 2 + 0] = a0;
        out[192 + g * 2 + 1] = a1;
    }
}

// ---------------- launch ----------------

extern "C" void kernel_launch(void* const* d_in, const int* in_sizes, int n_in,
                              void* d_out, int out_size, void* d_ws, size_t ws_size,
                              hipStream_t stream) {
    const float* x   = (const float*)d_in[0];           // [N, 256]
    const int* eidx  = (const int*)d_in[1];             // [2, E] flat
    const float* ew  = (const float*)d_in[2];           // [E]
    const int* batch = (const int*)d_in[3];             // [N]
    const float* W1  = (const float*)d_in[4];           // [256,128]
    const float* b1  = (const float*)d_in[5];
    const float* W2  = (const float*)d_in[6];           // [128,64]
    const float* b2  = (const float*)d_in[7];
    const float* l1w = (const float*)d_in[8];           // [64,64]
    const float* l1b = (const float*)d_in[9];
    const float* l2w = (const float*)d_in[10];          // [64,2]
    const float* l2b = (const float*)d_in[11];
    float* out = (float*)d_out;

    const int N = N_NODES, E = N_EDGES;
    const int* rows = eidx;
    const int* cols = eidx + E;

    // workspace layout (float offsets; 16B alignment for vector arrays)
    float* ws = (float*)d_ws;
    int*   ghist   = (int*)ws;                  // 391   -> pad to 512
    int*   gbase   = ghist + 512;               // 391   -> pad to 512
    int*   gcursor = gbase + 512;               // 391   -> pad to 512
    float* dinv    = (float*)(gcursor + 512);   // N
    int*   cnt     = (int*)(dinv + N);          // N
    int*   starts  = cnt + N;                   // N
    unsigned* w1t  = (unsigned*)(starts + N);   // 16384
    unsigned* w2t  = w1t + 16384;               // 4096
    int2*  csc_tmp = (int2*)(w2t + 4096);       // E int2 (16B-aligned)
    int2*  edges   = csc_tmp + E;               // E int2
    unsigned* xsb  = (unsigned*)(edges + E);    // N*64 dw
    unsigned* h1b  = xsb + (long)N * 64;        // N*64 dw
    float* pooled  = (float*)(h1b + (long)N * 64);  // 4096
    unsigned* hw2b = xsb;                       // reuse dead xsb: N*32 dw
    float* h2 = (float*)h1b;                    // reuse dead h1b: N*64 f32

    // 1. bucket histogram (block-aggregated atomics)
    hipMemsetAsync(ghist, 0, 512 * sizeof(int), stream);
    hist_kernel<<<NBLK_A, 256, 0, stream>>>(cols, ghist, E);

    // 2. bucket scan
    bucket_scan_kernel<<<1, 512, 0, stream>>>(ghist, gbase, gcursor);

    // 3. scatter into bucket-grouped tmp
    scatter_bucket_kernel<<<NBLK_A, 256, 0, stream>>>(rows, cols, ew, gcursor, csc_tmp, E);

    // 4. per-bucket node-level CSC + deg/dinv/starts/cnt
    build_csc_kernel<<<NBUCK, 256, 0, stream>>>(csc_tmp, gbase, ghist, edges, starts, cnt, dinv, N);

    // 5. weight prep
    transpose_bf_kernel<<<64, 256, 0, stream>>>(W1, w1t, NFEAT, NHID1);
    transpose_bf_kernel<<<16, 256, 0, stream>>>(W2, w2t, NHID1, NCLASS);

    // 6. GEMM1 (MFMA): xsb = bf16((x @ W1) * dinv[row])
    gemm_mfma<NHID1, NFEAT, false><<<(N + 127) / 128, 256, 0, stream>>>(
        x, w1t, dinv, (unsigned short*)xsb, N);

    // 7. gather layer 1: h1b = bf16(relu(dinv[c]*(agg + self) + b1))
    {
        long threads = (long)N * (NHID1 / 8);
        gather_agg_bf<NHID1, true, true><<<(threads + 255) / 256, 256, 0, stream>>>(
            xsb, edges, starts, cnt, dinv, b1, h1b, N);
    }

    // 8. GEMM2 (MFMA): hw2b = bf16((h1 @ W2) * dinv[row])  (into dead xsb region)
    gemm_mfma<NCLASS, NHID1, true><<<(N + 127) / 128, 256, 0, stream>>>(
        h1b, w2t, dinv, (unsigned short*)hw2b, N);

    // 9. gather layer 2: h2 = f32 relu(dinv[c]*(agg + self) + b2)  (into dead h1b region)
    {
        long threads = (long)N * (NCLASS / 8);
        gather_agg_bf<NCLASS, true, false><<<(threads + 255) / 256, 256, 0, stream>>>(
            hw2b, edges, starts, cnt, dinv, b2, h2, N);
    }

    // 10. pool
    hipMemsetAsync(pooled, 0, NUM_GRAPHS * NCLASS * sizeof(float), stream);
    {
        int blocks = (N + POOL_CHUNK - 1) / POOL_CHUNK;
        pool_kernel<<<blocks, 64, 0, stream>>>(h2, batch, pooled, N);
    }

    // 11. head
    head_kernel<<<1, 256, 0, stream>>>(pooled, l1w, l1b, l2w, l2b, out);
}